// Round 5
// baseline (185.919 us; speedup 1.0000x reference)
//
#include <hip/hip_runtime.h>
#include <hip/hip_bf16.h>

typedef __bf16 bf16_t;
typedef __bf16 bf16x4 __attribute__((ext_vector_type(4)));
typedef __bf16 bf16x8 __attribute__((ext_vector_type(8)));
typedef float f32x4 __attribute__((ext_vector_type(4)));

__device__ __forceinline__ void gload16(const void* g, void* l) {
  __builtin_amdgcn_global_load_lds((const __attribute__((address_space(1))) void*)g,
                                   (__attribute__((address_space(3))) void*)l, 16, 0, 0);
}

#define SB() __builtin_amdgcn_sched_barrier(0)
#define VMW(n) asm volatile("s_waitcnt vmcnt(" #n ")" ::: "memory")

// ---------------- prep: fold proj into w_qkv (q,k halves) ----------------
__global__ __launch_bounds__(256) void prep_qk(const float* __restrict__ w_qkv,
                                               const float* __restrict__ proj,
                                               bf16_t* __restrict__ WeffT) {
  const int half = blockIdx.x >> 3, h = blockIdx.x & 7;
  const int i0 = blockIdx.y * 64;
  __shared__ float P[64 * 64];   // [d][f] == proj[h] layout
  __shared__ float Wt[64][65];   // [ii][d], padded
  const int t = threadIdx.x;
  #pragma unroll
  for (int r = 0; r < 16; ++r) P[t + 256 * r] = proj[(size_t)h * 4096 + t + 256 * r];
  #pragma unroll
  for (int r = 0; r < 16; ++r) {
    const int idx = t + 256 * r;
    Wt[idx >> 6][idx & 63] =
        w_qkv[(size_t)(i0 + (idx >> 6)) * 1536 + half * 512 + h * 64 + (idx & 63)];
  }
  __syncthreads();
  const int i = t & 63, fg = t >> 6;
  for (int f = fg; f < 64; f += 4) {
    float s = 0.f;
    #pragma unroll
    for (int d = 0; d < 64; ++d) s += Wt[i][d] * P[d * 64 + f];
    WeffT[(size_t)(half * 512 + h * 64 + f) * 512 + i0 + i] = (bf16_t)s;
  }
}

// ---------------- prep: v passthrough transpose ----------------
__global__ __launch_bounds__(256) void prep_v(const float* __restrict__ w_qkv,
                                              bf16_t* __restrict__ WeffT) {
  __shared__ bf16_t tile[32][33];
  const int i0 = blockIdx.x * 32, n0 = blockIdx.y * 32;
  const int tn = threadIdx.x & 31, ti = threadIdx.x >> 5;
  #pragma unroll
  for (int p = 0; p < 4; ++p) {
    const int i = ti + p * 8;
    tile[i][tn] = (bf16_t)w_qkv[(size_t)(i0 + i) * 1536 + 1024 + n0 + tn];
  }
  __syncthreads();
  #pragma unroll
  for (int p = 0; p < 4; ++p) {
    const int n = ti + p * 8;
    WeffT[(size_t)(1024 + n0 + n) * 512 + i0 + tn] = tile[tn][n];
  }
}

// ---------------- cast x (f32) -> bf16 ----------------
__global__ __launch_bounds__(256) void cast_x(const f32x4* __restrict__ x,
                                              bf16x4* __restrict__ xb, int n4) {
  int i = blockIdx.x * 256 + threadIdx.x;
  if (i < n4) {
    f32x4 v = x[i];
    bf16x4 o;
    #pragma unroll
    for (int j = 0; j < 4; ++j) o[j] = (bf16_t)v[j];
    xb[i] = o;
  }
}

// ==================== QKV GEMM, 256x256 tile, counted-vmcnt pipeline ====================
// 768 blocks x 512 threads (8 waves = 2 feat-halves x 4 token-quads), XCD-chunked.
// bid -> (tb = bid/6 token tile, fb = bid%6 feat tile). C = x[256 tok] . WeffT[256 ft]^T.
// K=512, BK=32 -> 16 K-tiles; 4 LDS slots per operand (stage tile t+3 while computing t).
// vmcnt ledger (2 loads/stage-call): prologue issues A0 B0 A1 B1 A2 B2 (12 loads),
// vmcnt(8) -> tile0 landed. Loop tile t: ph0 stages A(t+3), ph1 stages B(t+3);
// boundary wait at t.ph1: issued = 4t+16 loads, need tiles<=t+1 = 4t+8 -> vmcnt(8)
// for t<=12, then 4 (t=13), 0 (t=14). Slot rotation (t%4 read, (t+3)%4 write) +
// per-phase barriers make WAR safe. Main-tile swizzle: 16B unit ^= (row>>1)&3.
__global__ __launch_bounds__(512, 2) void gemm_qkv8(const bf16_t* __restrict__ x_bf,
                                                    const bf16_t* __restrict__ WeffT,
                                                    bf16_t* __restrict__ q_phi,
                                                    bf16_t* __restrict__ kT,
                                                    bf16_t* __restrict__ vT) {
  __shared__ alignas(16) char smem[131072];  // x slots [0,64K), WeffT slots [64K,128K)
  const int t = threadIdx.x;
  const int wid = t >> 6, l = t & 63;
  const int wr = wid >> 2, wc = wid & 3;          // wr: feat half, wc: token quad
  const int lrow = l & 15, lkb = l >> 4;          // lkb 0..3 (8-bf16 k-slot)
  const int hw = blockIdx.x;
  const int bid = (hw & 7) * 96 + (hw >> 3);      // XCD-chunked, 768 = 8*96
  const int tb = bid / 6, fb = bid % 6;
  const size_t tok0 = (size_t)tb * 256;
  const int f0 = fb * 256;
  const bf16_t* Ap = x_bf + tok0 * 512;
  const bf16_t* Bp = WeffT + (size_t)f0 * 512;

  // staging: thread t -> LDS byte t*16 (rows 0..127) and +8192 (rows 128..255)
  // of a [256 rows][32 k] tile (64B rows, 4 x 16B units). source unit pre-swizzled.
  const int sr = t >> 2, su = t & 3;
  const int f_sr = (sr >> 1) & 3;                 // same for sr and sr+128
  const size_t a_off0 = (size_t)sr * 512 + ((su ^ f_sr) * 8);
  const size_t a_off1 = (size_t)(sr + 128) * 512 + ((su ^ f_sr) * 8);

  auto stageA = [&](int s) {
    char* dst = smem + (s & 3) * 16384;
    gload16(Ap + a_off0 + s * 32, dst + t * 16);
    gload16(Ap + a_off1 + s * 32, dst + 8192 + t * 16);
  };
  auto stageB = [&](int s) {
    char* dst = smem + 65536 + (s & 3) * 16384;
    gload16(Bp + a_off0 + s * 32, dst + t * 16);
    gload16(Bp + a_off1 + s * 32, dst + 8192 + t * 16);
  };

  // ds_read byte offsets within a slot (swizzled)
  int woff[8], xoff[4];
  #pragma unroll
  for (int m = 0; m < 8; ++m) {
    const int r = wr * 128 + m * 16 + lrow;       // WeffT (feat) row
    woff[m] = r * 64 + ((lkb ^ ((r >> 1) & 3)) << 4);
  }
  #pragma unroll
  for (int n = 0; n < 4; ++n) {
    const int r = wc * 64 + n * 16 + lrow;        // x (token) row
    xoff[n] = r * 64 + ((lkb ^ ((r >> 1) & 3)) << 4);
  }

  f32x4 acc[8][4];
  #pragma unroll
  for (int m = 0; m < 8; ++m)
    #pragma unroll
    for (int n = 0; n < 4; ++n) acc[m][n] = f32x4{0.f, 0.f, 0.f, 0.f};

  // prologue: tiles 0,1,2
  stageA(0); stageB(0); stageA(1); stageB(1); stageA(2); stageB(2);
  VMW(8);
  SB(); __builtin_amdgcn_s_barrier(); SB();

  bf16x8 xf[4];
  #pragma unroll
  for (int kt = 0; kt < 16; ++kt) {
    const char* Xs = smem + (kt & 3) * 16384;
    const char* Ws = smem + 65536 + (kt & 3) * 16384;
    bf16x8 wf[4];
    // ---- phase 0: feat-frags m0-3 x all token-frags ----
    #pragma unroll
    for (int m = 0; m < 4; ++m) wf[m] = *(const bf16x8*)(Ws + woff[m]);
    #pragma unroll
    for (int n = 0; n < 4; ++n) xf[n] = *(const bf16x8*)(Xs + xoff[n]);
    if (kt + 3 < 16) stageA(kt + 3);
    SB(); __builtin_amdgcn_s_barrier(); SB();
    __builtin_amdgcn_s_setprio(1);
    #pragma unroll
    for (int m = 0; m < 4; ++m)
      #pragma unroll
      for (int n = 0; n < 4; ++n)
        acc[m][n] = __builtin_amdgcn_mfma_f32_16x16x32_bf16(wf[m], xf[n], acc[m][n], 0, 0, 0);
    __builtin_amdgcn_s_setprio(0);
    SB(); __builtin_amdgcn_s_barrier(); SB();
    // ---- phase 1: feat-frags m4-7 (reuse xf) ----
    #pragma unroll
    for (int m = 0; m < 4; ++m) wf[m] = *(const bf16x8*)(Ws + woff[4 + m]);
    if (kt + 3 < 16) stageB(kt + 3);
    if (kt <= 12) { VMW(8); } else if (kt == 13) { VMW(4); } else if (kt == 14) { VMW(0); }
    SB(); __builtin_amdgcn_s_barrier(); SB();
    __builtin_amdgcn_s_setprio(1);
    #pragma unroll
    for (int m = 0; m < 4; ++m)
      #pragma unroll
      for (int n = 0; n < 4; ++n)
        acc[4 + m][n] = __builtin_amdgcn_mfma_f32_16x16x32_bf16(wf[m], xf[n], acc[4 + m][n], 0, 0, 0);
    __builtin_amdgcn_s_setprio(0);
    SB(); __builtin_amdgcn_s_barrier(); SB();
  }

  // ---- epilogue: restage C[256 tok][256 ft] bf16 in LDS (swz unit ^= (row^(row>>3))&7) ----
  const bool doElu = (fb < 4);
  #pragma unroll
  for (int m = 0; m < 8; ++m) {
    const int feat = wr * 128 + m * 16 + lkb * 4;
    const int ub = feat >> 3, bo = (feat & 7) * 2;
    #pragma unroll
    for (int n = 0; n < 4; ++n) {
      const int trow = wc * 64 + n * 16 + lrow;
      bf16x4 o;
      #pragma unroll
      for (int j = 0; j < 4; ++j) {
        float v = acc[m][n][j];
        if (doElu) v = v > 0.f ? v + 1.f : __expf(v);
        o[j] = (bf16_t)v;
      }
      const int s = (trow ^ (trow >> 3)) & 7;
      *(bf16x4*)(smem + trow * 512 + ((ub ^ s) << 4) + bo) = o;
    }
  }
  __syncthreads();
  if (fb < 2) {
    // q: rows = tokens, coalesced bf16x8
    #pragma unroll
    for (int p = 0; p < 16; ++p) {
      const int flat = p * 512 + t;
      const int trow = flat >> 5, u = flat & 31;
      const int s = (trow ^ (trow >> 3)) & 7;
      bf16x8 vv = *(const bf16x8*)(smem + trow * 512 + ((u ^ s) << 4));
      *(bf16x8*)&q_phi[(tok0 + trow) * 512 + f0 + u * 8] = vv;
    }
  } else {
    // k/v: transposed out, 8 scalar LDS reads -> bf16x8 store (256B runs per feat)
    const int b = (int)(tok0 >> 12);
    const int nn0 = (int)(tok0 & 4095);
    bf16_t* base = (fb < 4) ? (kT + ((size_t)(b * 512 + (fb - 2) * 256)) * 4096)
                            : (vT + ((size_t)(b * 512 + (fb - 4) * 256)) * 4096);
    #pragma unroll
    for (int p = 0; p < 16; ++p) {
      const int fl = (p & 7) * 32 + (t >> 4);
      const int tg = (p >> 3) * 16 + (t & 15);
      const int ub = fl >> 3, bo = (fl & 7) * 2;
      bf16x8 vv;
      #pragma unroll
      for (int j = 0; j < 8; ++j) {
        const int tok = tg * 8 + j;
        const int s = (tok ^ (tok >> 3)) & 7;
        vv[j] = *(const bf16_t*)(smem + tok * 512 + ((ub ^ s) << 4) + bo);
      }
      *(bf16x8*)(base + (size_t)fl * 4096 + nn0 + tg * 8) = vv;
    }
  }
}

// ---------------- kv[f][d] = sum_n kT[f][n]*vT[d][n]; ksum[f] = sum_n kT[f][n] ----
__global__ __launch_bounds__(256) void kv_mfma(const bf16_t* __restrict__ kT,
                                               const bf16_t* __restrict__ vT,
                                               float* __restrict__ kv,
                                               float* __restrict__ ksum) {
  const int bh = blockIdx.x;
  const int nbase = blockIdx.y * 512;
  __shared__ alignas(16) char smem[32768];  // 2 bufs x (K 8K + V 8K)
  const int t = threadIdx.x, w = t >> 6, l = t & 63;
  const int wr = w >> 1, wc = w & 1;
  const int lrow = l & 15, lkb = l >> 4;
  const int st_r = l >> 3;
  const int st_c = ((l & 7) ^ st_r) * 8;
  const bf16_t* Kp = kT + (size_t)bh * 64 * 4096;
  const bf16_t* Vp = vT + (size_t)bh * 64 * 4096;

  f32x4 acc[2][2];
  #pragma unroll
  for (int m = 0; m < 2; ++m)
    #pragma unroll
    for (int n = 0; n < 2; ++n) acc[m][n] = f32x4{0.f, 0.f, 0.f, 0.f};
  float ksf[2] = {0.f, 0.f};

  #pragma unroll
  for (int c = 0; c < 2; ++c) {
    const int q8 = w * 2 + c;
    gload16(Kp + (size_t)(q8 * 8 + st_r) * 4096 + nbase + st_c, smem + q8 * 1024);
    gload16(Vp + (size_t)(q8 * 8 + st_r) * 4096 + nbase + st_c, smem + 8192 + q8 * 1024);
  }
  __syncthreads();

  int cur = 0;
  for (int st = 0; st < 8; ++st) {
    if (st < 7) {
      char* nb = smem + (cur ^ 1) * 16384;
      const int nb2 = nbase + (st + 1) * 64;
      #pragma unroll
      for (int c = 0; c < 2; ++c) {
        const int q8 = w * 2 + c;
        gload16(Kp + (size_t)(q8 * 8 + st_r) * 4096 + nb2 + st_c, nb + q8 * 1024);
        gload16(Vp + (size_t)(q8 * 8 + st_r) * 4096 + nb2 + st_c, nb + 8192 + q8 * 1024);
      }
    }
    const char* KsB = smem + cur * 16384;
    const char* VsB = KsB + 8192;
    bf16x8 af[2][2], bf[2][2];
    #pragma unroll
    for (int m = 0; m < 2; ++m) {
      const int r = wr * 32 + m * 16 + lrow;
      #pragma unroll
      for (int kk = 0; kk < 2; ++kk) {
        const int kb = lkb + kk * 4;
        af[m][kk] = *(const bf16x8*)(KsB + r * 128 + (((kb ^ (r & 7)) & 7) << 4));
      }
    }
    #pragma unroll
    for (int n = 0; n < 2; ++n) {
      const int r = wc * 32 + n * 16 + lrow;
      #pragma unroll
      for (int kk = 0; kk < 2; ++kk) {
        const int kb = lkb + kk * 4;
        bf[n][kk] = *(const bf16x8*)(VsB + r * 128 + (((kb ^ (r & 7)) & 7) << 4));
      }
    }
    #pragma unroll
    for (int m = 0; m < 2; ++m)
      #pragma unroll
      for (int n = 0; n < 2; ++n) {
        acc[m][n] = __builtin_amdgcn_mfma_f32_16x16x32_bf16(af[m][0], bf[n][0], acc[m][n], 0, 0, 0);
        acc[m][n] = __builtin_amdgcn_mfma_f32_16x16x32_bf16(af[m][1], bf[n][1], acc[m][n], 0, 0, 0);
      }
    if (wc == 0) {
      #pragma unroll
      for (int m = 0; m < 2; ++m)
        #pragma unroll
        for (int kk = 0; kk < 2; ++kk)
          #pragma unroll
          for (int j = 0; j < 8; ++j) ksf[m] += (float)af[m][kk][j];
    }
    __syncthreads();
    cur ^= 1;
  }

  float* kvp = kv + (size_t)bh * 4096;
  #pragma unroll
  for (int m = 0; m < 2; ++m)
    #pragma unroll
    for (int n = 0; n < 2; ++n)
      #pragma unroll
      for (int j = 0; j < 4; ++j)
        atomicAdd(&kvp[(wr * 32 + m * 16 + lkb * 4 + j) * 64 + wc * 32 + n * 16 + lrow],
                  acc[m][n][j]);
  if (wc == 0) {
    #pragma unroll
    for (int m = 0; m < 2; ++m) {
      float s = ksf[m];
      s += __shfl_xor(s, 16);
      s += __shfl_xor(s, 32);
      if (l < 16) atomicAdd(&ksum[(size_t)bh * 64 + wr * 32 + m * 16 + l], s);
    }
  }
}

// ---------------- W2T[b][j][h*64+f] = sum_d kv[b,h,f,d] * w_proj[h*64+d][j] ----------------
__global__ __launch_bounds__(256) void w2_kernel(const float* __restrict__ kv,
                                                 const float* __restrict__ w_proj,
                                                 bf16_t* __restrict__ W2T) {
  const int bh = blockIdx.x, b = bh >> 3, h = bh & 7;
  const int j0 = blockIdx.y * 64;
  const int t = threadIdx.x;
  __shared__ float kvs[64][64];
  __shared__ float wps[64][64];
  const float* kvp = kv + (size_t)bh * 4096;
  #pragma unroll
  for (int i = 0; i < 16; ++i) ((float*)kvs)[t + 256 * i] = kvp[t + 256 * i];
  {
    const int d = t >> 2, c16 = (t & 3) * 16;
    const float* src = w_proj + (size_t)(h * 64 + d) * 512 + j0 + c16;
    #pragma unroll
    for (int j = 0; j < 16; ++j) wps[d][c16 + j] = src[j];
  }
  __syncthreads();
  const int fq = t >> 4, jq = t & 15;
  float acc[4][4] = {};
  for (int d = 0; d < 64; ++d) {
    float kf[4], wj[4];
    #pragma unroll
    for (int i = 0; i < 4; ++i) kf[i] = kvs[fq * 4 + i][d];
    #pragma unroll
    for (int i = 0; i < 4; ++i) wj[i] = wps[d][jq * 4 + i];
    #pragma unroll
    for (int i = 0; i < 4; ++i)
      #pragma unroll
      for (int j = 0; j < 4; ++j) acc[i][j] += kf[i] * wj[j];
  }
  #pragma unroll
  for (int j = 0; j < 4; ++j)
    #pragma unroll
    for (int i = 0; i < 4; ++i)
      W2T[((size_t)b * 512 + j0 + jq * 4 + j) * 512 + h * 64 + fq * 4 + i] = (bf16_t)acc[i][j];
}

// ---------------- zq[row][h*64+f] = qphi * (1 / sum_f qphi*ksum) (per head) ----------------
__global__ __launch_bounds__(256) void zq_kernel(const bf16_t* __restrict__ qphi,
                                                 const float* __restrict__ ksum,
                                                 bf16_t* __restrict__ zq) {
  const int row = blockIdx.x * 4 + (threadIdx.x >> 6);
  const int l = threadIdx.x & 63;
  const int b = row >> 12;
  const int h = l >> 3, f8 = (l & 7) * 8;
  const bf16_t* src = qphi + (size_t)row * 512 + h * 64 + f8;
  bf16x8 v = *(const bf16x8*)src;
  const float* ks = ksum + ((size_t)b * 8 + h) * 64 + f8;
  float part = 0.f;
  float vf[8];
  #pragma unroll
  for (int j = 0; j < 8; ++j) { vf[j] = (float)v[j]; part += vf[j] * ks[j]; }
  part += __shfl_xor(part, 1);
  part += __shfl_xor(part, 2);
  part += __shfl_xor(part, 4);
  const float z = 1.f / part;
  bf16x8 o;
  #pragma unroll
  for (int j = 0; j < 8; ++j) o[j] = (bf16_t)(vf[j] * z);
  *(bf16x8*)(zq + (size_t)row * 512 + h * 64 + f8) = o;
}

// ==================== output GEMM: out[z][token][j] = zq . W2T^T + bias ====================
__global__ __launch_bounds__(256) void gemm_out(const bf16_t* __restrict__ W2T,
                                                const bf16_t* __restrict__ zq,
                                                float* __restrict__ Cout,
                                                const float* __restrict__ bias) {
  constexpr int K = 512, BK = 64;
  __shared__ alignas(16) char smem[65536];
  const int t = threadIdx.x, w = t >> 6, l = t & 63;
  const int hw = blockIdx.x;
  const int bid = (hw & 7) * 128 + (hw >> 3);   // 1024/8=128
  const int z = bid >> 7;
  const int rem = bid & 127;
  const int qblk = rem >> 2, pblk = rem & 3;
  const size_t tok0 = (size_t)qblk * 128;
  const int pj0 = pblk * 128;
  const bf16_t* Pp = W2T + ((size_t)z * 512 + pj0) * 512;
  const bf16_t* Qp = zq + ((size_t)z * 4096 + tok0) * 512;

  const int wr = w >> 1, wc = w & 1;
  const int lrow = l & 15, lkb = l >> 4;
  const int st_r = l >> 3;
  const int st_c = ((l & 7) ^ st_r) * 8;

  f32x4 acc[4][4];
  #pragma unroll
  for (int m = 0; m < 4; ++m)
    #pragma unroll
    for (int n = 0; n < 4; ++n) acc[m][n] = f32x4{0.f, 0.f, 0.f, 0.f};

  #pragma unroll
  for (int c = 0; c < 4; ++c) {
    const int q8 = c * 4 + w;
    gload16(Pp + (size_t)(q8 * 8 + st_r) * K + st_c, smem + q8 * 1024);
    gload16(Qp + (size_t)(q8 * 8 + st_r) * K + st_c, smem + 16384 + q8 * 1024);
  }
  __syncthreads();

  int cur = 0;
  for (int kt = 0; kt < K; kt += BK) {
    if (kt + BK < K) {
      char* nb = smem + (cur ^ 1) * 32768;
      #pragma unroll
      for (int c = 0; c < 4; ++c) {
        const int q8 = c * 4 + w;
        gload16(Pp + (size_t)(q8 * 8 + st_r) * K + kt + BK + st_c, nb + q8 * 1024);
        gload16(Qp + (size_t)(q8 * 8 + st_r) * K + kt + BK + st_c, nb + 16384 + q8 * 1024);
      }
    }
    const char* PsB = smem + cur * 32768;
    const char* QsB = PsB + 16384;
    bf16x8 pf[4][2], qf[4][2];
    #pragma unroll
    for (int m = 0; m < 4; ++m) {
      const int r = wr * 64 + m * 16 + lrow;
      #pragma unroll
      for (int kk = 0; kk < 2; ++kk) {
        const int kb = lkb + kk * 4;
        pf[m][kk] = *(const bf16x8*)(PsB + r * 128 + (((kb ^ (r & 7)) & 7) << 4));
      }
    }
    #pragma unroll
    for (int n = 0; n < 4; ++n) {
      const int r = wc * 64 + n * 16 + lrow;
      #pragma unroll
      for (int kk = 0; kk < 2; ++kk) {
        const int kb = lkb + kk * 4;
        qf[n][kk] = *(const bf16x8*)(QsB + r * 128 + (((kb ^ (r & 7)) & 7) << 4));
      }
    }
    #pragma unroll
    for (int m = 0; m < 4; ++m)
      #pragma unroll
      for (int n = 0; n < 4; ++n) {
        acc[m][n] = __builtin_amdgcn_mfma_f32_16x16x32_bf16(pf[m][0], qf[n][0], acc[m][n], 0, 0, 0);
        acc[m][n] = __builtin_amdgcn_mfma_f32_16x16x32_bf16(pf[m][1], qf[n][1], acc[m][n], 0, 0, 0);
      }
    __syncthreads();
    cur ^= 1;
  }

  float* ep = (float*)smem;
  #pragma unroll
  for (int p = 0; p < 2; ++p) {
    if (p) __syncthreads();
    #pragma unroll
    for (int nn2 = 0; nn2 < 2; ++nn2) {
      const int n = p * 2 + nn2;
      const int r6 = wc * 32 + (n & 1) * 16 + lrow;
      #pragma unroll
      for (int m = 0; m < 4; ++m) {
        const int pr0 = wr * 64 + m * 16 + lkb * 4;
        f32x4 v = acc[m][n];
        const f32x4 bv = *(const f32x4*)&bias[pj0 + pr0];
        #pragma unroll
        for (int j = 0; j < 4; ++j) v[j] += bv[j];
        const int u = pr0 >> 2;
        *(f32x4*)((char*)ep + r6 * 512 + ((u ^ (r6 & 31)) << 4)) = v;
      }
    }
    __syncthreads();
    #pragma unroll
    for (int i = 0; i < 8; ++i) {
      const int flat = i * 256 + t;
      const int r6 = flat >> 5, u2 = flat & 31;
      f32x4 v = *(const f32x4*)((char*)ep + r6 * 512 + ((u2 ^ (r6 & 31)) << 4));
      const int qc = (r6 >> 5) * 64 + p * 32 + (r6 & 31);
      *(f32x4*)&Cout[((size_t)z * 4096 + tok0 + qc) * 512 + pj0 + u2 * 4] = v;
    }
  }
}

extern "C" void kernel_launch(void* const* d_in, const int* in_sizes, int n_in,
                              void* d_out, int out_size, void* d_ws, size_t ws_size,
                              hipStream_t stream) {
  const float* x      = (const float*)d_in[0];
  const float* w_qkv  = (const float*)d_in[1];
  const float* proj   = (const float*)d_in[2];
  const float* w_proj = (const float*)d_in[3];
  const float* b_proj = (const float*)d_in[4];
  float* out = (float*)d_out;
  char* ws = (char*)d_ws;

  // workspace layout (bytes)
  bf16_t* x_bf  = (bf16_t*)(ws + 0);           // 32768*512*2  = 33,554,432
  bf16_t* WeffT = (bf16_t*)(ws + 33554432);    // 1536*512*2   =  1,572,864
  bf16_t* q_phi = (bf16_t*)(ws + 35127296);    // 32768*512*2  = 33,554,432
  bf16_t* kT    = (bf16_t*)(ws + 68681728);    // 64*64*4096*2 = 33,554,432
  bf16_t* vT    = (bf16_t*)(ws + 102236160);   // 64*64*4096*2 = 33,554,432
  float*  kv    = (float*)(ws + 135790592);    // 64*64*64*4   =  1,048,576
  float*  ksum  = (float*)(ws + 136839168);    // 64*64*4      =     16,384
  bf16_t* W2T   = (bf16_t*)(ws + 136855552);   // 8*512*512*2  =  4,194,304
  bf16_t* zq    = (bf16_t*)(ws + 141049856);   // 32768*512*2  = 33,554,432

  prep_qk<<<dim3(16, 8), 256, 0, stream>>>(w_qkv, proj, WeffT);
  prep_v<<<dim3(16, 16), 256, 0, stream>>>(w_qkv, WeffT);
  cast_x<<<16384, 256, 0, stream>>>((const f32x4*)x, (bf16x4*)x_bf, 4194304);
  gemm_qkv8<<<768, 512, 0, stream>>>(x_bf, WeffT, q_phi, kT, vT);
  hipMemsetAsync(kv, 0, 1048576 + 16384, stream);
  kv_mfma<<<dim3(64, 8), 256, 0, stream>>>(kT, vT, kv, ksum);
  w2_kernel<<<dim3(64, 8), 256, 0, stream>>>(kv, w_proj, W2T);
  zq_kernel<<<8192, 256, 0, stream>>>(q_phi, ksum, zq);
  gemm_out<<<1024, 256, 0, stream>>>(W2T, zq, out, b_proj);
}

// Round 6
// 184.825 us; speedup vs baseline: 1.0059x; 1.0059x over previous
//
#include <hip/hip_runtime.h>
#include <hip/hip_bf16.h>

typedef __bf16 bf16_t;
typedef __bf16 bf16x4 __attribute__((ext_vector_type(4)));
typedef __bf16 bf16x8 __attribute__((ext_vector_type(8)));
typedef float f32x4 __attribute__((ext_vector_type(4)));

__device__ __forceinline__ void gload16(const void* g, void* l) {
  __builtin_amdgcn_global_load_lds((const __attribute__((address_space(1))) void*)g,
                                   (__attribute__((address_space(3))) void*)l, 16, 0, 0);
}

#define VMW(n) asm volatile("s_waitcnt vmcnt(" #n ")" ::: "memory")

// ---------------- prep: fold proj into w_qkv (q,k halves) ----------------
__global__ __launch_bounds__(256) void prep_qk(const float* __restrict__ w_qkv,
                                               const float* __restrict__ proj,
                                               bf16_t* __restrict__ WeffT) {
  const int half = blockIdx.x >> 3, h = blockIdx.x & 7;
  const int i0 = blockIdx.y * 64;
  __shared__ float P[64 * 64];   // [d][f] == proj[h] layout
  __shared__ float Wt[64][65];   // [ii][d], padded
  const int t = threadIdx.x;
  #pragma unroll
  for (int r = 0; r < 16; ++r) P[t + 256 * r] = proj[(size_t)h * 4096 + t + 256 * r];
  #pragma unroll
  for (int r = 0; r < 16; ++r) {
    const int idx = t + 256 * r;
    Wt[idx >> 6][idx & 63] =
        w_qkv[(size_t)(i0 + (idx >> 6)) * 1536 + half * 512 + h * 64 + (idx & 63)];
  }
  __syncthreads();
  const int i = t & 63, fg = t >> 6;
  for (int f = fg; f < 64; f += 4) {
    float s = 0.f;
    #pragma unroll
    for (int d = 0; d < 64; ++d) s += Wt[i][d] * P[d * 64 + f];
    WeffT[(size_t)(half * 512 + h * 64 + f) * 512 + i0 + i] = (bf16_t)s;
  }
}

// ---------------- prep: v passthrough transpose ----------------
__global__ __launch_bounds__(256) void prep_v(const float* __restrict__ w_qkv,
                                              bf16_t* __restrict__ WeffT) {
  __shared__ bf16_t tile[32][33];
  const int i0 = blockIdx.x * 32, n0 = blockIdx.y * 32;
  const int tn = threadIdx.x & 31, ti = threadIdx.x >> 5;
  #pragma unroll
  for (int p = 0; p < 4; ++p) {
    const int i = ti + p * 8;
    tile[i][tn] = (bf16_t)w_qkv[(size_t)(i0 + i) * 1536 + 1024 + n0 + tn];
  }
  __syncthreads();
  #pragma unroll
  for (int p = 0; p < 4; ++p) {
    const int n = ti + p * 8;
    WeffT[(size_t)(1024 + n0 + n) * 512 + i0 + tn] = tile[tn][n];
  }
}

// ---------------- cast x (f32) -> bf16 ----------------
__global__ __launch_bounds__(256) void cast_x(const f32x4* __restrict__ x,
                                              bf16x4* __restrict__ xb, int n4) {
  int i = blockIdx.x * 256 + threadIdx.x;
  if (i < n4) {
    f32x4 v = x[i];
    bf16x4 o;
    #pragma unroll
    for (int j = 0; j < 4; ++j) o[j] = (bf16_t)v[j];
    xb[i] = o;
  }
}

// ==================== QKV GEMM, 256x256 tile, counted-vmcnt pipeline (v2) ====================
// 768 blocks x 512 threads (8 waves = 2 feat-halves x 4 token-quads), XCD-chunked.
// K=512, BK=32 -> 16 K-tiles; 4 LDS slots per operand; stage slot kt+3 while computing kt.
// Schedule per iter kt (v2 — no sched_barriers, ONE barrier + ONE counted vmcnt):
//   reads(slot kt&3: wf0-3, xf) ; stageA(kt+3) ; setprio{16 MFMA} ;
//   reads(wf4-7) ; stageB(kt+3) ; setprio{16 MFMA} ; VMW ; s_barrier.
// Ledger (4 loads/slot, A=2+B=2): after iter kt stages, outstanding <= slots
// kt+1..kt+3 = 12 -> VMW(8) leaves kt+2,kt+3 in flight, slot kt+1 landed.
// Tail: kt=13 -> VMW(4), kt=14 -> VMW(0). WAR: iter kt writes slot (kt+3)&3 =
// slot read at iter kt-1; end-of-iter barrier separates those. Loads therefore
// span 3 K-tiles across barriers (T4) instead of draining per tile.
__global__ __launch_bounds__(512, 2) void gemm_qkv8(const bf16_t* __restrict__ x_bf,
                                                    const bf16_t* __restrict__ WeffT,
                                                    bf16_t* __restrict__ q_phi,
                                                    bf16_t* __restrict__ kT,
                                                    bf16_t* __restrict__ vT) {
  __shared__ alignas(16) char smem[131072];  // x slots [0,64K), WeffT slots [64K,128K)
  const int t = threadIdx.x;
  const int wid = t >> 6, l = t & 63;
  const int wr = wid >> 2, wc = wid & 3;          // wr: feat half, wc: token quad
  const int lrow = l & 15, lkb = l >> 4;          // lkb 0..3 (8-bf16 k-slot)
  const int hw = blockIdx.x;
  const int bid = (hw & 7) * 96 + (hw >> 3);      // XCD-chunked, 768 = 8*96
  const int tb = bid / 6, fb = bid % 6;
  const size_t tok0 = (size_t)tb * 256;
  const int f0 = fb * 256;
  const bf16_t* Ap = x_bf + tok0 * 512;
  const bf16_t* Bp = WeffT + (size_t)f0 * 512;

  // staging: thread t -> LDS byte t*16 (rows 0..127) and +8192 (rows 128..255)
  // of a [256 rows][32 k] tile (64B rows, 4 x 16B units). source unit pre-swizzled.
  const int sr = t >> 2, su = t & 3;
  const int f_sr = (sr >> 1) & 3;                 // same for sr and sr+128
  const size_t a_off0 = (size_t)sr * 512 + ((su ^ f_sr) * 8);
  const size_t a_off1 = (size_t)(sr + 128) * 512 + ((su ^ f_sr) * 8);

  auto stageA = [&](int s) {
    char* dst = smem + (s & 3) * 16384;
    gload16(Ap + a_off0 + s * 32, dst + t * 16);
    gload16(Ap + a_off1 + s * 32, dst + 8192 + t * 16);
  };
  auto stageB = [&](int s) {
    char* dst = smem + 65536 + (s & 3) * 16384;
    gload16(Bp + a_off0 + s * 32, dst + t * 16);
    gload16(Bp + a_off1 + s * 32, dst + 8192 + t * 16);
  };

  // ds_read byte offsets within a slot (swizzled)
  int woff[8], xoff[4];
  #pragma unroll
  for (int m = 0; m < 8; ++m) {
    const int r = wr * 128 + m * 16 + lrow;       // WeffT (feat) row
    woff[m] = r * 64 + ((lkb ^ ((r >> 1) & 3)) << 4);
  }
  #pragma unroll
  for (int n = 0; n < 4; ++n) {
    const int r = wc * 64 + n * 16 + lrow;        // x (token) row
    xoff[n] = r * 64 + ((lkb ^ ((r >> 1) & 3)) << 4);
  }

  f32x4 acc[8][4];
  #pragma unroll
  for (int m = 0; m < 8; ++m)
    #pragma unroll
    for (int n = 0; n < 4; ++n) acc[m][n] = f32x4{0.f, 0.f, 0.f, 0.f};

  // prologue: slots 0,1,2 (12 loads); VMW(8) -> slot 0 landed
  stageA(0); stageB(0); stageA(1); stageB(1); stageA(2); stageB(2);
  VMW(8);
  __builtin_amdgcn_s_barrier();

  #pragma unroll
  for (int kt = 0; kt < 16; ++kt) {
    const char* Xs = smem + (kt & 3) * 16384;
    const char* Ws = smem + 65536 + (kt & 3) * 16384;
    bf16x8 wf[4], xf[4];
    // ---- phase 0: feat-frags m0-3 x all token-frags ----
    #pragma unroll
    for (int m = 0; m < 4; ++m) wf[m] = *(const bf16x8*)(Ws + woff[m]);
    #pragma unroll
    for (int n = 0; n < 4; ++n) xf[n] = *(const bf16x8*)(Xs + xoff[n]);
    if (kt + 3 < 16) stageA(kt + 3);
    __builtin_amdgcn_s_setprio(1);
    #pragma unroll
    for (int m = 0; m < 4; ++m)
      #pragma unroll
      for (int n = 0; n < 4; ++n)
        acc[m][n] = __builtin_amdgcn_mfma_f32_16x16x32_bf16(wf[m], xf[n], acc[m][n], 0, 0, 0);
    __builtin_amdgcn_s_setprio(0);
    // ---- phase 1: feat-frags m4-7 (reuse xf) ----
    #pragma unroll
    for (int m = 0; m < 4; ++m) wf[m] = *(const bf16x8*)(Ws + woff[4 + m]);
    if (kt + 3 < 16) stageB(kt + 3);
    __builtin_amdgcn_s_setprio(1);
    #pragma unroll
    for (int m = 0; m < 4; ++m)
      #pragma unroll
      for (int n = 0; n < 4; ++n)
        acc[4 + m][n] = __builtin_amdgcn_mfma_f32_16x16x32_bf16(wf[m], xf[n], acc[4 + m][n], 0, 0, 0);
    __builtin_amdgcn_s_setprio(0);
    // ---- end of iter: counted wait (slot kt+1 landed), one barrier ----
    if (kt <= 12) { VMW(8); } else if (kt == 13) { VMW(4); } else if (kt == 14) { VMW(0); }
    __builtin_amdgcn_s_barrier();
  }

  // ---- epilogue: restage C[256 tok][256 ft] bf16 in LDS (swz unit ^= (row^(row>>3))&7) ----
  const bool doElu = (fb < 4);
  #pragma unroll
  for (int m = 0; m < 8; ++m) {
    const int feat = wr * 128 + m * 16 + lkb * 4;
    const int ub = feat >> 3, bo = (feat & 7) * 2;
    #pragma unroll
    for (int n = 0; n < 4; ++n) {
      const int trow = wc * 64 + n * 16 + lrow;
      bf16x4 o;
      #pragma unroll
      for (int j = 0; j < 4; ++j) {
        float v = acc[m][n][j];
        if (doElu) v = v > 0.f ? v + 1.f : __expf(v);
        o[j] = (bf16_t)v;
      }
      const int s = (trow ^ (trow >> 3)) & 7;
      *(bf16x4*)(smem + trow * 512 + ((ub ^ s) << 4) + bo) = o;
    }
  }
  __syncthreads();
  if (fb < 2) {
    // q: rows = tokens, coalesced bf16x8
    #pragma unroll
    for (int p = 0; p < 16; ++p) {
      const int flat = p * 512 + t;
      const int trow = flat >> 5, u = flat & 31;
      const int s = (trow ^ (trow >> 3)) & 7;
      bf16x8 vv = *(const bf16x8*)(smem + trow * 512 + ((u ^ s) << 4));
      *(bf16x8*)&q_phi[(tok0 + trow) * 512 + f0 + u * 8] = vv;
    }
  } else {
    // k/v: transposed out, 8 scalar LDS reads -> bf16x8 store (256B runs per feat)
    const int b = (int)(tok0 >> 12);
    const int nn0 = (int)(tok0 & 4095);
    bf16_t* base = (fb < 4) ? (kT + ((size_t)(b * 512 + (fb - 2) * 256)) * 4096)
                            : (vT + ((size_t)(b * 512 + (fb - 4) * 256)) * 4096);
    #pragma unroll
    for (int p = 0; p < 16; ++p) {
      const int fl = (p & 7) * 32 + (t >> 4);
      const int tg = (p >> 3) * 16 + (t & 15);
      const int ub = fl >> 3, bo = (fl & 7) * 2;
      bf16x8 vv;
      #pragma unroll
      for (int j = 0; j < 8; ++j) {
        const int tok = tg * 8 + j;
        const int s = (tok ^ (tok >> 3)) & 7;
        vv[j] = *(const bf16_t*)(smem + tok * 512 + ((ub ^ s) << 4) + bo);
      }
      *(bf16x8*)(base + (size_t)fl * 4096 + nn0 + tg * 8) = vv;
    }
  }
}

// ---------------- kv[f][d] = sum_n kT[f][n]*vT[d][n]; ksum[f] = sum_n kT[f][n] ----
__global__ __launch_bounds__(256) void kv_mfma(const bf16_t* __restrict__ kT,
                                               const bf16_t* __restrict__ vT,
                                               float* __restrict__ kv,
                                               float* __restrict__ ksum) {
  const int bh = blockIdx.x;
  const int nbase = blockIdx.y * 512;
  __shared__ alignas(16) char smem[32768];  // 2 bufs x (K 8K + V 8K)
  const int t = threadIdx.x, w = t >> 6, l = t & 63;
  const int wr = w >> 1, wc = w & 1;
  const int lrow = l & 15, lkb = l >> 4;
  const int st_r = l >> 3;
  const int st_c = ((l & 7) ^ st_r) * 8;
  const bf16_t* Kp = kT + (size_t)bh * 64 * 4096;
  const bf16_t* Vp = vT + (size_t)bh * 64 * 4096;

  f32x4 acc[2][2];
  #pragma unroll
  for (int m = 0; m < 2; ++m)
    #pragma unroll
    for (int n = 0; n < 2; ++n) acc[m][n] = f32x4{0.f, 0.f, 0.f, 0.f};
  float ksf[2] = {0.f, 0.f};

  #pragma unroll
  for (int c = 0; c < 2; ++c) {
    const int q8 = w * 2 + c;
    gload16(Kp + (size_t)(q8 * 8 + st_r) * 4096 + nbase + st_c, smem + q8 * 1024);
    gload16(Vp + (size_t)(q8 * 8 + st_r) * 4096 + nbase + st_c, smem + 8192 + q8 * 1024);
  }
  __syncthreads();

  int cur = 0;
  for (int st = 0; st < 8; ++st) {
    if (st < 7) {
      char* nb = smem + (cur ^ 1) * 16384;
      const int nb2 = nbase + (st + 1) * 64;
      #pragma unroll
      for (int c = 0; c < 2; ++c) {
        const int q8 = w * 2 + c;
        gload16(Kp + (size_t)(q8 * 8 + st_r) * 4096 + nb2 + st_c, nb + q8 * 1024);
        gload16(Vp + (size_t)(q8 * 8 + st_r) * 4096 + nb2 + st_c, nb + 8192 + q8 * 1024);
      }
    }
    const char* KsB = smem + cur * 16384;
    const char* VsB = KsB + 8192;
    bf16x8 af[2][2], bf[2][2];
    #pragma unroll
    for (int m = 0; m < 2; ++m) {
      const int r = wr * 32 + m * 16 + lrow;
      #pragma unroll
      for (int kk = 0; kk < 2; ++kk) {
        const int kb = lkb + kk * 4;
        af[m][kk] = *(const bf16x8*)(KsB + r * 128 + (((kb ^ (r & 7)) & 7) << 4));
      }
    }
    #pragma unroll
    for (int n = 0; n < 2; ++n) {
      const int r = wc * 32 + n * 16 + lrow;
      #pragma unroll
      for (int kk = 0; kk < 2; ++kk) {
        const int kb = lkb + kk * 4;
        bf[n][kk] = *(const bf16x8*)(VsB + r * 128 + (((kb ^ (r & 7)) & 7) << 4));
      }
    }
    #pragma unroll
    for (int m = 0; m < 2; ++m)
      #pragma unroll
      for (int n = 0; n < 2; ++n) {
        acc[m][n] = __builtin_amdgcn_mfma_f32_16x16x32_bf16(af[m][0], bf[n][0], acc[m][n], 0, 0, 0);
        acc[m][n] = __builtin_amdgcn_mfma_f32_16x16x32_bf16(af[m][1], bf[n][1], acc[m][n], 0, 0, 0);
      }
    if (wc == 0) {
      #pragma unroll
      for (int m = 0; m < 2; ++m)
        #pragma unroll
        for (int kk = 0; kk < 2; ++kk)
          #pragma unroll
          for (int j = 0; j < 8; ++j) ksf[m] += (float)af[m][kk][j];
    }
    __syncthreads();
    cur ^= 1;
  }

  float* kvp = kv + (size_t)bh * 4096;
  #pragma unroll
  for (int m = 0; m < 2; ++m)
    #pragma unroll
    for (int n = 0; n < 2; ++n)
      #pragma unroll
      for (int j = 0; j < 4; ++j)
        atomicAdd(&kvp[(wr * 32 + m * 16 + lkb * 4 + j) * 64 + wc * 32 + n * 16 + lrow],
                  acc[m][n][j]);
  if (wc == 0) {
    #pragma unroll
    for (int m = 0; m < 2; ++m) {
      float s = ksf[m];
      s += __shfl_xor(s, 16);
      s += __shfl_xor(s, 32);
      if (l < 16) atomicAdd(&ksum[(size_t)bh * 64 + wr * 32 + m * 16 + l], s);
    }
  }
}

// ---------------- W2T[b][j][h*64+f] = sum_d kv[b,h,f,d] * w_proj[h*64+d][j] ----------------
__global__ __launch_bounds__(256) void w2_kernel(const float* __restrict__ kv,
                                                 const float* __restrict__ w_proj,
                                                 bf16_t* __restrict__ W2T) {
  const int bh = blockIdx.x, b = bh >> 3, h = bh & 7;
  const int j0 = blockIdx.y * 64;
  const int t = threadIdx.x;
  __shared__ float kvs[64][64];
  __shared__ float wps[64][64];
  const float* kvp = kv + (size_t)bh * 4096;
  #pragma unroll
  for (int i = 0; i < 16; ++i) ((float*)kvs)[t + 256 * i] = kvp[t + 256 * i];
  {
    const int d = t >> 2, c16 = (t & 3) * 16;
    const float* src = w_proj + (size_t)(h * 64 + d) * 512 + j0 + c16;
    #pragma unroll
    for (int j = 0; j < 16; ++j) wps[d][c16 + j] = src[j];
  }
  __syncthreads();
  const int fq = t >> 4, jq = t & 15;
  float acc[4][4] = {};
  for (int d = 0; d < 64; ++d) {
    float kf[4], wj[4];
    #pragma unroll
    for (int i = 0; i < 4; ++i) kf[i] = kvs[fq * 4 + i][d];
    #pragma unroll
    for (int i = 0; i < 4; ++i) wj[i] = wps[d][jq * 4 + i];
    #pragma unroll
    for (int i = 0; i < 4; ++i)
      #pragma unroll
      for (int j = 0; j < 4; ++j) acc[i][j] += kf[i] * wj[j];
  }
  #pragma unroll
  for (int j = 0; j < 4; ++j)
    #pragma unroll
    for (int i = 0; i < 4; ++i)
      W2T[((size_t)b * 512 + j0 + jq * 4 + j) * 512 + h * 64 + fq * 4 + i] = (bf16_t)acc[i][j];
}

// ---------------- zq[row][h*64+f] = qphi * (1 / sum_f qphi*ksum) (per head) ----------------
__global__ __launch_bounds__(256) void zq_kernel(const bf16_t* __restrict__ qphi,
                                                 const float* __restrict__ ksum,
                                                 bf16_t* __restrict__ zq) {
  const int row = blockIdx.x * 4 + (threadIdx.x >> 6);
  const int l = threadIdx.x & 63;
  const int b = row >> 12;
  const int h = l >> 3, f8 = (l & 7) * 8;
  const bf16_t* src = qphi + (size_t)row * 512 + h * 64 + f8;
  bf16x8 v = *(const bf16x8*)src;
  const float* ks = ksum + ((size_t)b * 8 + h) * 64 + f8;
  float part = 0.f;
  float vf[8];
  #pragma unroll
  for (int j = 0; j < 8; ++j) { vf[j] = (float)v[j]; part += vf[j] * ks[j]; }
  part += __shfl_xor(part, 1);
  part += __shfl_xor(part, 2);
  part += __shfl_xor(part, 4);
  const float z = 1.f / part;
  bf16x8 o;
  #pragma unroll
  for (int j = 0; j < 8; ++j) o[j] = (bf16_t)(vf[j] * z);
  *(bf16x8*)(zq + (size_t)row * 512 + h * 64 + f8) = o;
}

// ==================== output GEMM: out[z][token][j] = zq . W2T^T + bias ====================
__global__ __launch_bounds__(256) void gemm_out(const bf16_t* __restrict__ W2T,
                                                const bf16_t* __restrict__ zq,
                                                float* __restrict__ Cout,
                                                const float* __restrict__ bias) {
  constexpr int K = 512, BK = 64;
  __shared__ alignas(16) char smem[65536];
  const int t = threadIdx.x, w = t >> 6, l = t & 63;
  const int hw = blockIdx.x;
  const int bid = (hw & 7) * 128 + (hw >> 3);   // 1024/8=128
  const int z = bid >> 7;
  const int rem = bid & 127;
  const int qblk = rem >> 2, pblk = rem & 3;
  const size_t tok0 = (size_t)qblk * 128;
  const int pj0 = pblk * 128;
  const bf16_t* Pp = W2T + ((size_t)z * 512 + pj0) * 512;
  const bf16_t* Qp = zq + ((size_t)z * 4096 + tok0) * 512;

  const int wr = w >> 1, wc = w & 1;
  const int lrow = l & 15, lkb = l >> 4;
  const int st_r = l >> 3;
  const int st_c = ((l & 7) ^ st_r) * 8;

  f32x4 acc[4][4];
  #pragma unroll
  for (int m = 0; m < 4; ++m)
    #pragma unroll
    for (int n = 0; n < 4; ++n) acc[m][n] = f32x4{0.f, 0.f, 0.f, 0.f};

  #pragma unroll
  for (int c = 0; c < 4; ++c) {
    const int q8 = c * 4 + w;
    gload16(Pp + (size_t)(q8 * 8 + st_r) * K + st_c, smem + q8 * 1024);
    gload16(Qp + (size_t)(q8 * 8 + st_r) * K + st_c, smem + 16384 + q8 * 1024);
  }
  __syncthreads();

  int cur = 0;
  for (int kt = 0; kt < K; kt += BK) {
    if (kt + BK < K) {
      char* nb = smem + (cur ^ 1) * 32768;
      #pragma unroll
      for (int c = 0; c < 4; ++c) {
        const int q8 = c * 4 + w;
        gload16(Pp + (size_t)(q8 * 8 + st_r) * K + kt + BK + st_c, nb + q8 * 1024);
        gload16(Qp + (size_t)(q8 * 8 + st_r) * K + kt + BK + st_c, nb + 16384 + q8 * 1024);
      }
    }
    const char* PsB = smem + cur * 32768;
    const char* QsB = PsB + 16384;
    bf16x8 pf[4][2], qf[4][2];
    #pragma unroll
    for (int m = 0; m < 4; ++m) {
      const int r = wr * 64 + m * 16 + lrow;
      #pragma unroll
      for (int kk = 0; kk < 2; ++kk) {
        const int kb = lkb + kk * 4;
        pf[m][kk] = *(const bf16x8*)(PsB + r * 128 + (((kb ^ (r & 7)) & 7) << 4));
      }
    }
    #pragma unroll
    for (int n = 0; n < 4; ++n) {
      const int r = wc * 64 + n * 16 + lrow;
      #pragma unroll
      for (int kk = 0; kk < 2; ++kk) {
        const int kb = lkb + kk * 4;
        qf[n][kk] = *(const bf16x8*)(QsB + r * 128 + (((kb ^ (r & 7)) & 7) << 4));
      }
    }
    #pragma unroll
    for (int m = 0; m < 4; ++m)
      #pragma unroll
      for (int n = 0; n < 4; ++n) {
        acc[m][n] = __builtin_amdgcn_mfma_f32_16x16x32_bf16(pf[m][0], qf[n][0], acc[m][n], 0, 0, 0);
        acc[m][n] = __builtin_amdgcn_mfma_f32_16x16x32_bf16(pf[m][1], qf[n][1], acc[m][n], 0, 0, 0);
      }
    __syncthreads();
    cur ^= 1;
  }

  float* ep = (float*)smem;
  #pragma unroll
  for (int p = 0; p < 2; ++p) {
    if (p) __syncthreads();
    #pragma unroll
    for (int nn2 = 0; nn2 < 2; ++nn2) {
      const int n = p * 2 + nn2;
      const int r6 = wc * 32 + (n & 1) * 16 + lrow;
      #pragma unroll
      for (int m = 0; m < 4; ++m) {
        const int pr0 = wr * 64 + m * 16 + lkb * 4;
        f32x4 v = acc[m][n];
        const f32x4 bv = *(const f32x4*)&bias[pj0 + pr0];
        #pragma unroll
        for (int j = 0; j < 4; ++j) v[j] += bv[j];
        const int u = pr0 >> 2;
        *(f32x4*)((char*)ep + r6 * 512 + ((u ^ (r6 & 31)) << 4)) = v;
      }
    }
    __syncthreads();
    #pragma unroll
    for (int i = 0; i < 8; ++i) {
      const int flat = i * 256 + t;
      const int r6 = flat >> 5, u2 = flat & 31;
      f32x4 v = *(const f32x4*)((char*)ep + r6 * 512 + ((u2 ^ (r6 & 31)) << 4));
      const int qc = (r6 >> 5) * 64 + p * 32 + (r6 & 31);
      *(f32x4*)&Cout[((size_t)z * 4096 + tok0 + qc) * 512 + pj0 + u2 * 4] = v;
    }
  }
}

extern "C" void kernel_launch(void* const* d_in, const int* in_sizes, int n_in,
                              void* d_out, int out_size, void* d_ws, size_t ws_size,
                              hipStream_t stream) {
  const float* x      = (const float*)d_in[0];
  const float* w_qkv  = (const float*)d_in[1];
  const float* proj   = (const float*)d_in[2];
  const float* w_proj = (const float*)d_in[3];
  const float* b_proj = (const float*)d_in[4];
  float* out = (float*)d_out;
  char* ws = (char*)d_ws;

  // workspace layout (bytes)
  bf16_t* x_bf  = (bf16_t*)(ws + 0);           // 32768*512*2  = 33,554,432
  bf16_t* WeffT = (bf16_t*)(ws + 33554432);    // 1536*512*2   =  1,572,864
  bf16_t* q_phi = (bf16_t*)(ws + 35127296);    // 32768*512*2  = 33,554,432
  bf16_t* kT    = (bf16_t*)(ws + 68681728);    // 64*64*4096*2 = 33,554,432
  bf16_t* vT    = (bf16_t*)(ws + 102236160);   // 64*64*4096*2 = 33,554,432
  float*  kv    = (float*)(ws + 135790592);    // 64*64*64*4   =  1,048,576
  float*  ksum  = (float*)(ws + 136839168);    // 64*64*4      =     16,384
  bf16_t* W2T   = (bf16_t*)(ws + 136855552);   // 8*512*512*2  =  4,194,304
  bf16_t* zq    = (bf16_t*)(ws + 141049856);   // 32768*512*2  = 33,554,432

  prep_qk<<<dim3(16, 8), 256, 0, stream>>>(w_qkv, proj, WeffT);
  prep_v<<<dim3(16, 16), 256, 0, stream>>>(w_qkv, WeffT);
  cast_x<<<16384, 256, 0, stream>>>((const f32x4*)x, (bf16x4*)x_bf, 4194304);
  gemm_qkv8<<<768, 512, 0, stream>>>(x_bf, WeffT, q_phi, kT, vT);
  hipMemsetAsync(kv, 0, 1048576 + 16384, stream);
  kv_mfma<<<dim3(64, 8), 256, 0, stream>>>(kT, vT, kv, ksum);
  w2_kernel<<<dim3(64, 8), 256, 0, stream>>>(kv, w_proj, W2T);
  zq_kernel<<<8192, 256, 0, stream>>>(q_phi, ksum, zq);
  gemm_out<<<1024, 256, 0, stream>>>(W2T, zq, out, b_proj);
}

// Round 7
// 177.063 us; speedup vs baseline: 1.0500x; 1.0438x over previous
//
#include <hip/hip_runtime.h>
#include <hip/hip_bf16.h>

typedef __bf16 bf16_t;
typedef __bf16 bf16x4 __attribute__((ext_vector_type(4)));
typedef __bf16 bf16x8 __attribute__((ext_vector_type(8)));
typedef float f32x2 __attribute__((ext_vector_type(2)));
typedef float f32x4 __attribute__((ext_vector_type(4)));

__device__ __forceinline__ void gload16(const void* g, void* l) {
  __builtin_amdgcn_global_load_lds((const __attribute__((address_space(1))) void*)g,
                                   (__attribute__((address_space(3))) void*)l, 16, 0, 0);
}

#define VMW(n) asm volatile("s_waitcnt vmcnt(" #n ")" ::: "memory")
#define LGKM0() asm volatile("s_waitcnt lgkmcnt(0)" ::: "memory")

// ---------------- prep: fold proj into w_qkv (q,k halves) ----------------
__global__ __launch_bounds__(256) void prep_qk(const float* __restrict__ w_qkv,
                                               const float* __restrict__ proj,
                                               bf16_t* __restrict__ WeffT) {
  const int half = blockIdx.x >> 3, h = blockIdx.x & 7;
  const int i0 = blockIdx.y * 64;
  __shared__ float P[64 * 64];   // [d][f] == proj[h] layout
  __shared__ float Wt[64][65];   // [ii][d], padded
  const int t = threadIdx.x;
  #pragma unroll
  for (int r = 0; r < 16; ++r) P[t + 256 * r] = proj[(size_t)h * 4096 + t + 256 * r];
  #pragma unroll
  for (int r = 0; r < 16; ++r) {
    const int idx = t + 256 * r;
    Wt[idx >> 6][idx & 63] =
        w_qkv[(size_t)(i0 + (idx >> 6)) * 1536 + half * 512 + h * 64 + (idx & 63)];
  }
  __syncthreads();
  const int i = t & 63, fg = t >> 6;
  for (int f = fg; f < 64; f += 4) {
    float s = 0.f;
    #pragma unroll
    for (int d = 0; d < 64; ++d) s += Wt[i][d] * P[d * 64 + f];
    WeffT[(size_t)(half * 512 + h * 64 + f) * 512 + i0 + i] = (bf16_t)s;
  }
}

// ---------------- prep: v passthrough transpose ----------------
__global__ __launch_bounds__(256) void prep_v(const float* __restrict__ w_qkv,
                                              bf16_t* __restrict__ WeffT) {
  __shared__ bf16_t tile[32][33];
  const int i0 = blockIdx.x * 32, n0 = blockIdx.y * 32;
  const int tn = threadIdx.x & 31, ti = threadIdx.x >> 5;
  #pragma unroll
  for (int p = 0; p < 4; ++p) {
    const int i = ti + p * 8;
    tile[i][tn] = (bf16_t)w_qkv[(size_t)(i0 + i) * 1536 + 1024 + n0 + tn];
  }
  __syncthreads();
  #pragma unroll
  for (int p = 0; p < 4; ++p) {
    const int n = ti + p * 8;
    WeffT[(size_t)(1024 + n0 + n) * 512 + i0 + tn] = tile[tn][n];
  }
}

// ==================== QKV GEMM v3: fused f32->bf16 A-staging ====================
// 768 blocks x 512 threads, XCD-chunked. C = x[256 tok] . WeffT[256 ft]^T, K=512,
// BK=32 -> 16 K-tiles. A (x, f32): reg-staged (global f32x4 loads -> cvt -> ds_write),
// 2 LDS slots. B (WeffT): global_load_lds, 3 slots, staged 2-ahead. LDS 80 KB ->
// 2 blocks/CU. Ledger: iter kt issues loadA(kt+1)[4] then stageB(kt+2)[2]; writeA's
// compiler-inserted wait for areg (vmcnt(2)) also lands B(kt+1) (older); explicit
// VMW keeps B(kt+2) in flight across the barrier (never drains mid-loop).
__global__ __launch_bounds__(512, 2) void gemm_qkv8(const float* __restrict__ x,
                                                    const bf16_t* __restrict__ WeffT,
                                                    bf16_t* __restrict__ q_phi,
                                                    bf16_t* __restrict__ kT,
                                                    bf16_t* __restrict__ vT) {
  __shared__ alignas(16) char smem[81920];  // A slots [0,32K) x2; B slots [32K,80K) x3
  const int t = threadIdx.x;
  const int wid = t >> 6, l = t & 63;
  const int wr = wid >> 2, wc = wid & 3;          // wr: feat half, wc: token quad
  const int lrow = l & 15, lkb = l >> 4;
  const int hw = blockIdx.x;
  const int bid = (hw & 7) * 96 + (hw >> 3);      // XCD-chunked, 768 = 8*96
  const int tb = bid / 6, fb = bid % 6;
  const size_t tok0 = (size_t)tb * 256;
  const int f0 = fb * 256;
  const float* Ap = x + tok0 * 512;
  const bf16_t* Bp = WeffT + (size_t)f0 * 512;

  // staging geometry: [256 rows][32 k] bf16 per slot (64B rows, 4x16B units),
  // unit swizzle u ^= (row>>1)&3. thread t -> row t>>2 (and +128), unit t&3.
  const int sr = t >> 2, su = t & 3;
  const int f_sr = (sr >> 1) & 3;
  const int scol = (su ^ f_sr) * 8;               // pre-swizzled source col (elements)

  f32x4 areg[4];
  auto loadA = [&](int s) {
    const float* p0 = Ap + (size_t)sr * 512 + scol + s * 32;
    const float* p1 = Ap + (size_t)(sr + 128) * 512 + scol + s * 32;
    areg[0] = *(const f32x4*)p0;
    areg[1] = *(const f32x4*)(p0 + 4);
    areg[2] = *(const f32x4*)p1;
    areg[3] = *(const f32x4*)(p1 + 4);
  };
  auto writeA = [&](int s) {
    char* dst = smem + (s & 1) * 16384;
    bf16x8 o0, o1;
    #pragma unroll
    for (int j = 0; j < 4; ++j) {
      o0[j] = (bf16_t)areg[0][j]; o0[4 + j] = (bf16_t)areg[1][j];
      o1[j] = (bf16_t)areg[2][j]; o1[4 + j] = (bf16_t)areg[3][j];
    }
    *(bf16x8*)(dst + t * 16) = o0;
    *(bf16x8*)(dst + 8192 + t * 16) = o1;
  };
  auto stageB = [&](int s) {
    char* dst = smem + 32768 + (s % 3) * 16384;
    gload16(Bp + (size_t)sr * 512 + scol + s * 32, dst + t * 16);
    gload16(Bp + (size_t)(sr + 128) * 512 + scol + s * 32, dst + 8192 + t * 16);
  };

  int woff[8], xoff[4];
  #pragma unroll
  for (int m = 0; m < 8; ++m) {
    const int r = wr * 128 + m * 16 + lrow;       // WeffT (feat) row
    woff[m] = r * 64 + ((lkb ^ ((r >> 1) & 3)) << 4);
  }
  #pragma unroll
  for (int n = 0; n < 4; ++n) {
    const int r = wc * 64 + n * 16 + lrow;        // x (token) row
    xoff[n] = r * 64 + ((lkb ^ ((r >> 1) & 3)) << 4);
  }

  f32x4 acc[8][4];
  #pragma unroll
  for (int m = 0; m < 8; ++m)
    #pragma unroll
    for (int n = 0; n < 4; ++n) acc[m][n] = f32x4{0.f, 0.f, 0.f, 0.f};

  // prologue: A0 regs; B0,B1 in flight; write A0; B0 landed (B1 stays in flight)
  loadA(0); stageB(0); stageB(1);
  writeA(0);
  VMW(2);
  LGKM0();
  __builtin_amdgcn_s_barrier();

  #pragma unroll
  for (int kt = 0; kt < 16; ++kt) {
    const char* Xs = smem + (kt & 1) * 16384;
    const char* Ws = smem + 32768 + (kt % 3) * 16384;
    bf16x8 wf[4], xf[4];
    #pragma unroll
    for (int m = 0; m < 4; ++m) wf[m] = *(const bf16x8*)(Ws + woff[m]);
    #pragma unroll
    for (int n = 0; n < 4; ++n) xf[n] = *(const bf16x8*)(Xs + xoff[n]);
    if (kt + 1 < 16) loadA(kt + 1);
    if (kt + 2 < 16) stageB(kt + 2);
    __builtin_amdgcn_s_setprio(1);
    #pragma unroll
    for (int m = 0; m < 4; ++m)
      #pragma unroll
      for (int n = 0; n < 4; ++n)
        acc[m][n] = __builtin_amdgcn_mfma_f32_16x16x32_bf16(wf[m], xf[n], acc[m][n], 0, 0, 0);
    __builtin_amdgcn_s_setprio(0);
    #pragma unroll
    for (int m = 0; m < 4; ++m) wf[m] = *(const bf16x8*)(Ws + woff[4 + m]);
    __builtin_amdgcn_s_setprio(1);
    #pragma unroll
    for (int m = 0; m < 4; ++m)
      #pragma unroll
      for (int n = 0; n < 4; ++n)
        acc[4 + m][n] = __builtin_amdgcn_mfma_f32_16x16x32_bf16(wf[m], xf[n], acc[4 + m][n], 0, 0, 0);
    __builtin_amdgcn_s_setprio(0);
    if (kt + 1 < 16) writeA(kt + 1);  // compiler waits areg; drains B(kt+1) too (older)
    if (kt <= 13) { VMW(2); } else if (kt == 14) { VMW(0); }
    LGKM0();
    __builtin_amdgcn_s_barrier();
  }

  // ---- epilogue: 2 phases of 128 tokens (64 KB restage each) ----
  const bool doElu = (fb < 4);
  const int b = (int)(tok0 >> 12);
  const int nn0 = (int)(tok0 & 4095);
  #pragma unroll
  for (int p = 0; p < 2; ++p) {
    if (p) __syncthreads();  // phase-0 reads done before phase-1 writes
    if ((wc >> 1) == p) {    // waves owning tokens [p*128, p*128+128)
      #pragma unroll
      for (int m = 0; m < 8; ++m) {
        const int feat = wr * 128 + m * 16 + lkb * 4;
        const int ub = feat >> 3, bo = (feat & 7) * 2;
        #pragma unroll
        for (int n = 0; n < 4; ++n) {
          const int trow = (wc & 1) * 64 + n * 16 + lrow;  // local token row 0..127
          bf16x4 o;
          #pragma unroll
          for (int j = 0; j < 4; ++j) {
            float v = acc[m][n][j];
            if (doElu) v = v > 0.f ? v + 1.f : __expf(v);
            o[j] = (bf16_t)v;
          }
          const int s = (trow ^ (trow >> 3)) & 7;
          *(bf16x4*)(smem + trow * 512 + ((ub ^ s) << 4) + bo) = o;
        }
      }
    }
    __syncthreads();
    if (fb < 2) {
      // q: rows = tokens, coalesced bf16x8
      #pragma unroll
      for (int i = 0; i < 8; ++i) {
        const int flat = i * 512 + t;
        const int trow = flat >> 5, u = flat & 31;
        const int s = (trow ^ (trow >> 3)) & 7;
        bf16x8 vv = *(const bf16x8*)(smem + trow * 512 + ((u ^ s) << 4));
        *(bf16x8*)&q_phi[(tok0 + p * 128 + trow) * 512 + f0 + u * 8] = vv;
      }
    } else {
      // k/v: transposed out, 8 scalar LDS reads -> bf16x8 store
      bf16_t* base = (fb < 4) ? (kT + ((size_t)(b * 512 + (fb - 2) * 256)) * 4096)
                              : (vT + ((size_t)(b * 512 + (fb - 4) * 256)) * 4096);
      #pragma unroll
      for (int i = 0; i < 8; ++i) {
        const int flat = i * 512 + t;
        const int fl = flat >> 4, tg = flat & 15;
        const int ub = fl >> 3, bo = (fl & 7) * 2;
        bf16x8 vv;
        #pragma unroll
        for (int j = 0; j < 8; ++j) {
          const int tok = tg * 8 + j;
          const int s = (tok ^ (tok >> 3)) & 7;
          vv[j] = *(const bf16_t*)(smem + tok * 512 + ((ub ^ s) << 4) + bo);
        }
        *(bf16x8*)(base + (size_t)fl * 4096 + nn0 + p * 128 + tg * 8) = vv;
      }
    }
  }
}

// ---------------- kv[f][d] = sum_n kT[f][n]*vT[d][n]; ksum[f] = sum_n kT[f][n] ----
__global__ __launch_bounds__(256) void kv_mfma(const bf16_t* __restrict__ kT,
                                               const bf16_t* __restrict__ vT,
                                               float* __restrict__ kv,
                                               float* __restrict__ ksum) {
  const int bh = blockIdx.x;
  const int nbase = blockIdx.y * 512;
  __shared__ alignas(16) char smem[32768];  // 2 bufs x (K 8K + V 8K)
  const int t = threadIdx.x, w = t >> 6, l = t & 63;
  const int wr = w >> 1, wc = w & 1;
  const int lrow = l & 15, lkb = l >> 4;
  const int st_r = l >> 3;
  const int st_c = ((l & 7) ^ st_r) * 8;
  const bf16_t* Kp = kT + (size_t)bh * 64 * 4096;
  const bf16_t* Vp = vT + (size_t)bh * 64 * 4096;

  f32x4 acc[2][2];
  #pragma unroll
  for (int m = 0; m < 2; ++m)
    #pragma unroll
    for (int n = 0; n < 2; ++n) acc[m][n] = f32x4{0.f, 0.f, 0.f, 0.f};
  float ksf[2] = {0.f, 0.f};

  #pragma unroll
  for (int c = 0; c < 2; ++c) {
    const int q8 = w * 2 + c;
    gload16(Kp + (size_t)(q8 * 8 + st_r) * 4096 + nbase + st_c, smem + q8 * 1024);
    gload16(Vp + (size_t)(q8 * 8 + st_r) * 4096 + nbase + st_c, smem + 8192 + q8 * 1024);
  }
  __syncthreads();

  int cur = 0;
  for (int st = 0; st < 8; ++st) {
    if (st < 7) {
      char* nb = smem + (cur ^ 1) * 16384;
      const int nb2 = nbase + (st + 1) * 64;
      #pragma unroll
      for (int c = 0; c < 2; ++c) {
        const int q8 = w * 2 + c;
        gload16(Kp + (size_t)(q8 * 8 + st_r) * 4096 + nb2 + st_c, nb + q8 * 1024);
        gload16(Vp + (size_t)(q8 * 8 + st_r) * 4096 + nb2 + st_c, nb + 8192 + q8 * 1024);
      }
    }
    const char* KsB = smem + cur * 16384;
    const char* VsB = KsB + 8192;
    bf16x8 af[2][2], bf[2][2];
    #pragma unroll
    for (int m = 0; m < 2; ++m) {
      const int r = wr * 32 + m * 16 + lrow;
      #pragma unroll
      for (int kk = 0; kk < 2; ++kk) {
        const int kb = lkb + kk * 4;
        af[m][kk] = *(const bf16x8*)(KsB + r * 128 + (((kb ^ (r & 7)) & 7) << 4));
      }
    }
    #pragma unroll
    for (int n = 0; n < 2; ++n) {
      const int r = wc * 32 + n * 16 + lrow;
      #pragma unroll
      for (int kk = 0; kk < 2; ++kk) {
        const int kb = lkb + kk * 4;
        bf[n][kk] = *(const bf16x8*)(VsB + r * 128 + (((kb ^ (r & 7)) & 7) << 4));
      }
    }
    #pragma unroll
    for (int m = 0; m < 2; ++m)
      #pragma unroll
      for (int n = 0; n < 2; ++n) {
        acc[m][n] = __builtin_amdgcn_mfma_f32_16x16x32_bf16(af[m][0], bf[n][0], acc[m][n], 0, 0, 0);
        acc[m][n] = __builtin_amdgcn_mfma_f32_16x16x32_bf16(af[m][1], bf[n][1], acc[m][n], 0, 0, 0);
      }
    if (wc == 0) {
      #pragma unroll
      for (int m = 0; m < 2; ++m)
        #pragma unroll
        for (int kk = 0; kk < 2; ++kk)
          #pragma unroll
          for (int j = 0; j < 8; ++j) ksf[m] += (float)af[m][kk][j];
    }
    __syncthreads();
    cur ^= 1;
  }

  float* kvp = kv + (size_t)bh * 4096;
  #pragma unroll
  for (int m = 0; m < 2; ++m)
    #pragma unroll
    for (int n = 0; n < 2; ++n)
      #pragma unroll
      for (int j = 0; j < 4; ++j)
        atomicAdd(&kvp[(wr * 32 + m * 16 + lkb * 4 + j) * 64 + wc * 32 + n * 16 + lrow],
                  acc[m][n][j]);
  if (wc == 0) {
    #pragma unroll
    for (int m = 0; m < 2; ++m) {
      float s = ksf[m];
      s += __shfl_xor(s, 16);
      s += __shfl_xor(s, 32);
      if (l < 16) atomicAdd(&ksum[(size_t)bh * 64 + wr * 32 + m * 16 + l], s);
    }
  }
}

// ---------------- W2T[b][j][h*64+f] = sum_d kv[b,h,f,d] * w_proj[h*64+d][j] ----------------
__global__ __launch_bounds__(256) void w2_kernel(const float* __restrict__ kv,
                                                 const float* __restrict__ w_proj,
                                                 bf16_t* __restrict__ W2T) {
  const int bh = blockIdx.x, b = bh >> 3, h = bh & 7;
  const int j0 = blockIdx.y * 64;
  const int t = threadIdx.x;
  __shared__ float kvs[64][64];
  __shared__ float wps[64][64];
  const float* kvp = kv + (size_t)bh * 4096;
  #pragma unroll
  for (int i = 0; i < 16; ++i) ((float*)kvs)[t + 256 * i] = kvp[t + 256 * i];
  {
    const int d = t >> 2, c16 = (t & 3) * 16;
    const float* src = w_proj + (size_t)(h * 64 + d) * 512 + j0 + c16;
    #pragma unroll
    for (int j = 0; j < 16; ++j) wps[d][c16 + j] = src[j];
  }
  __syncthreads();
  const int fq = t >> 4, jq = t & 15;
  float acc[4][4] = {};
  for (int d = 0; d < 64; ++d) {
    float kf[4], wj[4];
    #pragma unroll
    for (int i = 0; i < 4; ++i) kf[i] = kvs[fq * 4 + i][d];
    #pragma unroll
    for (int i = 0; i < 4; ++i) wj[i] = wps[d][jq * 4 + i];
    #pragma unroll
    for (int i = 0; i < 4; ++i)
      #pragma unroll
      for (int j = 0; j < 4; ++j) acc[i][j] += kf[i] * wj[j];
  }
  #pragma unroll
  for (int j = 0; j < 4; ++j)
    #pragma unroll
    for (int i = 0; i < 4; ++i)
      W2T[((size_t)b * 512 + j0 + jq * 4 + j) * 512 + h * 64 + fq * 4 + i] = (bf16_t)acc[i][j];
}

// ==================== output GEMM v2: fused z-scale (zq) in B-staging ====================
// out[z][token][j] = (qphi[token] * z[token,h]) . W2T[z]^T + bias. BK=64 = one head ->
// z[token,h] = 1/(qphi[tok, h*64..+64] . ksum[z, h*64..+64]) computable per K-chunk.
// A (W2T): gload_lds, 2 slots. B: reg-staged qphi + dot + scale + ds_write, 2 slots.
__global__ __launch_bounds__(256) void gemm_out(const bf16_t* __restrict__ W2T,
                                                const bf16_t* __restrict__ q_phi,
                                                const float* __restrict__ ksum,
                                                float* __restrict__ Cout,
                                                const float* __restrict__ bias) {
  __shared__ alignas(16) char smem[67584];  // A [0,32K) x2; B [32K,64K) x2; ksum [64K,66K)
  const int t = threadIdx.x, w = t >> 6, l = t & 63;
  const int hw = blockIdx.x;
  const int bid = (hw & 7) * 128 + (hw >> 3);   // 1024/8=128
  const int z = bid >> 7;
  const int rem = bid & 127;
  const int qblk = rem >> 2, pblk = rem & 3;
  const size_t tok0 = (size_t)qblk * 128;
  const int pj0 = pblk * 128;
  const bf16_t* Pp = W2T + ((size_t)z * 512 + pj0) * 512;

  const int wr = w >> 1, wc = w & 1;
  const int lrow = l & 15, lkb = l >> 4;
  const int st_r = l >> 3;
  const int st_c = ((l & 7) ^ st_r) * 8;
  const int token = t >> 1, half = t & 1;
  float* ks_lds = (float*)(smem + 65536);

  bf16x8 breg[4];
  auto loadB = [&](int c) {
    const bf16_t* p = q_phi + ((size_t)z * 4096 + tok0 + token) * 512 + c * 64 + half * 32;
    breg[0] = *(const bf16x8*)p;
    breg[1] = *(const bf16x8*)(p + 8);
    breg[2] = *(const bf16x8*)(p + 16);
    breg[3] = *(const bf16x8*)(p + 24);
  };
  auto stageA = [&](int s) {
    #pragma unroll
    for (int c = 0; c < 4; ++c) {
      const int q8 = c * 4 + w;
      gload16(Pp + (size_t)(q8 * 8 + st_r) * 512 + s * 64 + st_c,
              smem + (s & 1) * 16384 + q8 * 1024);
    }
  };
  auto procB = [&](int c) {
    const f32x4* ksv = (const f32x4*)(ks_lds + c * 64 + half * 32);
    float vals[32];
    float dot = 0.f;
    #pragma unroll
    for (int g = 0; g < 8; ++g) {
      const f32x4 kk = ksv[g];
      #pragma unroll
      for (int j = 0; j < 4; ++j) {
        const float v = (float)breg[g >> 1][(g & 1) * 4 + j];
        vals[g * 4 + j] = v;
        dot += v * kk[j];
      }
    }
    dot += __shfl_xor(dot, 1);  // lanes 2i,2i+1 share a token
    const float zz = 1.f / dot;
    char* dst = smem + 32768 + (c & 1) * 16384;
    #pragma unroll
    for (int g = 0; g < 4; ++g) {
      bf16x8 o;
      #pragma unroll
      for (int j = 0; j < 8; ++j) o[j] = (bf16_t)(vals[g * 8 + j] * zz);
      const int uk = half * 4 + g;
      *(bf16x8*)(dst + token * 128 + ((uk ^ (token & 7)) << 4)) = o;
    }
  };

  // prologue: ksum -> LDS; then chunk 0 staged
  {
    const f32x2 kk = *(const f32x2*)&ksum[(size_t)z * 512 + t * 2];
    *(f32x2*)&ks_lds[t * 2] = kk;
  }
  __syncthreads();
  loadB(0);
  stageA(0);
  procB(0);
  VMW(0);
  __syncthreads();

  f32x4 acc[4][4];
  #pragma unroll
  for (int m = 0; m < 4; ++m)
    #pragma unroll
    for (int n = 0; n < 4; ++n) acc[m][n] = f32x4{0.f, 0.f, 0.f, 0.f};

  for (int kt = 0; kt < 8; ++kt) {
    const char* PsB = smem + (kt & 1) * 16384;
    const char* QsB = smem + 32768 + (kt & 1) * 16384;
    bf16x8 pf[4][2], qf[4][2];
    #pragma unroll
    for (int m = 0; m < 4; ++m) {
      const int r = wr * 64 + m * 16 + lrow;
      #pragma unroll
      for (int kk = 0; kk < 2; ++kk) {
        const int kb = lkb + kk * 4;
        pf[m][kk] = *(const bf16x8*)(PsB + r * 128 + (((kb ^ (r & 7)) & 7) << 4));
      }
    }
    #pragma unroll
    for (int n = 0; n < 4; ++n) {
      const int r = wc * 64 + n * 16 + lrow;
      #pragma unroll
      for (int kk = 0; kk < 2; ++kk) {
        const int kb = lkb + kk * 4;
        qf[n][kk] = *(const bf16x8*)(QsB + r * 128 + (((kb ^ (r & 7)) & 7) << 4));
      }
    }
    if (kt + 1 < 8) { loadB(kt + 1); stageA(kt + 1); }
    #pragma unroll
    for (int m = 0; m < 4; ++m)
      #pragma unroll
      for (int n = 0; n < 4; ++n) {
        acc[m][n] = __builtin_amdgcn_mfma_f32_16x16x32_bf16(pf[m][0], qf[n][0], acc[m][n], 0, 0, 0);
        acc[m][n] = __builtin_amdgcn_mfma_f32_16x16x32_bf16(pf[m][1], qf[n][1], acc[m][n], 0, 0, 0);
      }
    if (kt + 1 < 8) { procB(kt + 1); VMW(0); }
    __syncthreads();
  }

  // epilogue: two phases of [64 token-rows][128 j] f32 (32 KB each) in smem[0,32K)
  float* ep = (float*)smem;
  #pragma unroll
  for (int p = 0; p < 2; ++p) {
    if (p) __syncthreads();
    #pragma unroll
    for (int nn2 = 0; nn2 < 2; ++nn2) {
      const int n = p * 2 + nn2;
      const int r6 = wc * 32 + (n & 1) * 16 + lrow;
      #pragma unroll
      for (int m = 0; m < 4; ++m) {
        const int pr0 = wr * 64 + m * 16 + lkb * 4;
        f32x4 v = acc[m][n];
        const f32x4 bv = *(const f32x4*)&bias[pj0 + pr0];
        #pragma unroll
        for (int j = 0; j < 4; ++j) v[j] += bv[j];
        const int u = pr0 >> 2;
        *(f32x4*)((char*)ep + r6 * 512 + ((u ^ (r6 & 31)) << 4)) = v;
      }
    }
    __syncthreads();
    #pragma unroll
    for (int i = 0; i < 8; ++i) {
      const int flat = i * 256 + t;
      const int r6 = flat >> 5, u2 = flat & 31;
      f32x4 v = *(const f32x4*)((char*)ep + r6 * 512 + ((u2 ^ (r6 & 31)) << 4));
      const int qc = (r6 >> 5) * 64 + p * 32 + (r6 & 31);
      *(f32x4*)&Cout[((size_t)z * 4096 + tok0 + qc) * 512 + pj0 + u2 * 4] = v;
    }
  }
}

extern "C" void kernel_launch(void* const* d_in, const int* in_sizes, int n_in,
                              void* d_out, int out_size, void* d_ws, size_t ws_size,
                              hipStream_t stream) {
  const float* x      = (const float*)d_in[0];
  const float* w_qkv  = (const float*)d_in[1];
  const float* proj   = (const float*)d_in[2];
  const float* w_proj = (const float*)d_in[3];
  const float* b_proj = (const float*)d_in[4];
  float* out = (float*)d_out;
  char* ws = (char*)d_ws;

  // workspace layout (bytes)
  bf16_t* WeffT = (bf16_t*)(ws + 0);           // 1536*512*2   =  1,572,864
  bf16_t* q_phi = (bf16_t*)(ws + 1572864);     // 32768*512*2  = 33,554,432
  bf16_t* kT    = (bf16_t*)(ws + 35127296);    // 64*64*4096*2 = 33,554,432
  bf16_t* vT    = (bf16_t*)(ws + 68681728);    // 64*64*4096*2 = 33,554,432
  float*  kv    = (float*)(ws + 102236160);    // 64*64*64*4   =  1,048,576
  float*  ksum  = (float*)(ws + 103284736);    // 64*64*4      =     16,384
  bf16_t* W2T   = (bf16_t*)(ws + 103301120);   // 8*512*512*2  =  4,194,304
                                               // total 107,495,424

  prep_qk<<<dim3(16, 8), 256, 0, stream>>>(w_qkv, proj, WeffT);
  prep_v<<<dim3(16, 16), 256, 0, stream>>>(w_qkv, WeffT);
  gemm_qkv8<<<768, 512, 0, stream>>>(x, WeffT, q_phi, kT, vT);
  hipMemsetAsync(kv, 0, 1048576 + 16384, stream);
  kv_mfma<<<dim3(64, 8), 256, 0, stream>>>(kT, vT, kv, ksum);
  w2_kernel<<<dim3(64, 8), 256, 0, stream>>>(kv, w_proj, W2T);
  gemm_out<<<1024, 256, 0, stream>>>(W2T, q_phi, ksum, out, b_proj);
}

// Round 8
// 171.150 us; speedup vs baseline: 1.0863x; 1.0345x over previous
//
#include <hip/hip_runtime.h>
#include <hip/hip_bf16.h>

typedef __bf16 bf16_t;
typedef __bf16 bf16x4 __attribute__((ext_vector_type(4)));
typedef __bf16 bf16x8 __attribute__((ext_vector_type(8)));
typedef float f32x2 __attribute__((ext_vector_type(2)));
typedef float f32x4 __attribute__((ext_vector_type(4)));

__device__ __forceinline__ void gload16(const void* g, void* l) {
  __builtin_amdgcn_global_load_lds((const __attribute__((address_space(1))) void*)g,
                                   (__attribute__((address_space(3))) void*)l, 16, 0, 0);
}

#define VMW(n) asm volatile("s_waitcnt vmcnt(" #n ")" ::: "memory")
#define LGKM0() asm volatile("s_waitcnt lgkmcnt(0)" ::: "memory")

// ---------------- prep: fold proj into w_qkv (q,k halves) ----------------
__global__ __launch_bounds__(256) void prep_qk(const float* __restrict__ w_qkv,
                                               const float* __restrict__ proj,
                                               bf16_t* __restrict__ WeffT) {
  const int half = blockIdx.x >> 3, h = blockIdx.x & 7;
  const int i0 = blockIdx.y * 64;
  __shared__ float P[64 * 64];   // [d][f] == proj[h] layout
  __shared__ float Wt[64][65];   // [ii][d], padded
  const int t = threadIdx.x;
  #pragma unroll
  for (int r = 0; r < 16; ++r) P[t + 256 * r] = proj[(size_t)h * 4096 + t + 256 * r];
  #pragma unroll
  for (int r = 0; r < 16; ++r) {
    const int idx = t + 256 * r;
    Wt[idx >> 6][idx & 63] =
        w_qkv[(size_t)(i0 + (idx >> 6)) * 1536 + half * 512 + h * 64 + (idx & 63)];
  }
  __syncthreads();
  const int i = t & 63, fg = t >> 6;
  for (int f = fg; f < 64; f += 4) {
    float s = 0.f;
    #pragma unroll
    for (int d = 0; d < 64; ++d) s += Wt[i][d] * P[d * 64 + f];
    WeffT[(size_t)(half * 512 + h * 64 + f) * 512 + i0 + i] = (bf16_t)s;
  }
}

// ---------------- prep: v passthrough transpose ----------------
__global__ __launch_bounds__(256) void prep_v(const float* __restrict__ w_qkv,
                                              bf16_t* __restrict__ WeffT) {
  __shared__ bf16_t tile[32][33];
  const int i0 = blockIdx.x * 32, n0 = blockIdx.y * 32;
  const int tn = threadIdx.x & 31, ti = threadIdx.x >> 5;
  #pragma unroll
  for (int p = 0; p < 4; ++p) {
    const int i = ti + p * 8;
    tile[i][tn] = (bf16_t)w_qkv[(size_t)(i0 + i) * 1536 + 1024 + n0 + tn];
  }
  __syncthreads();
  #pragma unroll
  for (int p = 0; p < 4; ++p) {
    const int n = ti + p * 8;
    WeffT[(size_t)(1024 + n0 + n) * 512 + i0 + tn] = tile[tn][n];
  }
}

// ==================== QKV GEMM v4: fused cast, reg-double-buffered A ====================
// 768 blocks x 512 threads, XCD-chunked. C = x[256 tok] . WeffT[256 ft]^T, K=512,
// BK=32 -> 16 K-tiles. A (x, f32): reg-staged with areg[2] double-buffer — loadA(kt+2)
// issued at iter kt, consumed by writeA(kt+2) at iter kt+1 (FULL iteration of latency
// hiding; R7's same-iter consume was the 124us regression). B (WeffT): gload_lds, 3
// slots, staged 2-ahead. Ledger: at writeA(kt+1), outstanding = A(kt+1)[4] B(kt+1)[2]
// -> implicit vmcnt(2) already satisfied in steady state. End of iter: outstanding
// B(kt+1)[2] A(kt+2)[4] B(kt+2)[2] = 8 -> VMW(6) retires exactly B(kt+1); A/B(kt+2)
// stay in flight across the barrier. Tail: VMW(6) kt<=13, VMW(0) kt==14.
__global__ __launch_bounds__(512, 2) void gemm_qkv8(const float* __restrict__ x,
                                                    const bf16_t* __restrict__ WeffT,
                                                    bf16_t* __restrict__ q_phi,
                                                    bf16_t* __restrict__ kT,
                                                    bf16_t* __restrict__ vT) {
  __shared__ alignas(16) char smem[81920];  // A slots [0,32K) x2; B slots [32K,80K) x3
  const int t = threadIdx.x;
  const int wid = t >> 6, l = t & 63;
  const int wr = wid >> 2, wc = wid & 3;          // wr: feat half, wc: token quad
  const int lrow = l & 15, lkb = l >> 4;
  const int hw = blockIdx.x;
  const int bid = (hw & 7) * 96 + (hw >> 3);      // XCD-chunked, 768 = 8*96
  const int tb = bid / 6, fb = bid % 6;
  const size_t tok0 = (size_t)tb * 256;
  const int f0 = fb * 256;
  const float* Ap = x + tok0 * 512;
  const bf16_t* Bp = WeffT + (size_t)f0 * 512;

  // staging geometry: [256 rows][32 k] bf16 per slot (64B rows, 4x16B units),
  // unit swizzle u ^= (row>>1)&3. thread t -> row t>>2 (and +128), unit t&3.
  const int sr = t >> 2, su = t & 3;
  const int f_sr = (sr >> 1) & 3;
  const int scol = (su ^ f_sr) * 8;               // pre-swizzled source col (elements)

  f32x4 areg[2][4];  // static indices after full unroll (rule #20)
  auto loadA = [&](int s) {
    const float* p0 = Ap + (size_t)sr * 512 + scol + s * 32;
    const float* p1 = Ap + (size_t)(sr + 128) * 512 + scol + s * 32;
    areg[s & 1][0] = *(const f32x4*)p0;
    areg[s & 1][1] = *(const f32x4*)(p0 + 4);
    areg[s & 1][2] = *(const f32x4*)p1;
    areg[s & 1][3] = *(const f32x4*)(p1 + 4);
  };
  auto writeA = [&](int s) {
    char* dst = smem + (s & 1) * 16384;
    bf16x8 o0, o1;
    #pragma unroll
    for (int j = 0; j < 4; ++j) {
      o0[j] = (bf16_t)areg[s & 1][0][j]; o0[4 + j] = (bf16_t)areg[s & 1][1][j];
      o1[j] = (bf16_t)areg[s & 1][2][j]; o1[4 + j] = (bf16_t)areg[s & 1][3][j];
    }
    *(bf16x8*)(dst + t * 16) = o0;
    *(bf16x8*)(dst + 8192 + t * 16) = o1;
  };
  auto stageB = [&](int s) {
    char* dst = smem + 32768 + (s % 3) * 16384;
    gload16(Bp + (size_t)sr * 512 + scol + s * 32, dst + t * 16);
    gload16(Bp + (size_t)(sr + 128) * 512 + scol + s * 32, dst + 8192 + t * 16);
  };

  int woff[8], xoff[4];
  #pragma unroll
  for (int m = 0; m < 8; ++m) {
    const int r = wr * 128 + m * 16 + lrow;       // WeffT (feat) row
    woff[m] = r * 64 + ((lkb ^ ((r >> 1) & 3)) << 4);
  }
  #pragma unroll
  for (int n = 0; n < 4; ++n) {
    const int r = wc * 64 + n * 16 + lrow;        // x (token) row
    xoff[n] = r * 64 + ((lkb ^ ((r >> 1) & 3)) << 4);
  }

  f32x4 acc[8][4];
  #pragma unroll
  for (int m = 0; m < 8; ++m)
    #pragma unroll
    for (int n = 0; n < 4; ++n) acc[m][n] = f32x4{0.f, 0.f, 0.f, 0.f};

  // prologue: A0 -> regs -> slot0 (one-time drain); A1 regs + B0,B1 in flight.
  loadA(0);
  writeA(0);           // compiler inserts vmcnt(0) for areg[0]
  loadA(1);            // oldest outstanding
  stageB(0); stageB(1);
  VMW(2);              // A1 + B0 landed; B1 stays in flight
  LGKM0();
  __builtin_amdgcn_s_barrier();

  #pragma unroll
  for (int kt = 0; kt < 16; ++kt) {
    const char* Xs = smem + (kt & 1) * 16384;
    const char* Ws = smem + 32768 + (kt % 3) * 16384;
    bf16x8 wf[4], xf[4];
    #pragma unroll
    for (int m = 0; m < 4; ++m) wf[m] = *(const bf16x8*)(Ws + woff[m]);
    #pragma unroll
    for (int n = 0; n < 4; ++n) xf[n] = *(const bf16x8*)(Xs + xoff[n]);
    if (kt + 1 < 16) writeA(kt + 1);              // regs loaded a full iter ago
    if (kt + 2 < 16) { loadA(kt + 2); stageB(kt + 2); }
    __builtin_amdgcn_s_setprio(1);
    #pragma unroll
    for (int m = 0; m < 4; ++m)
      #pragma unroll
      for (int n = 0; n < 4; ++n)
        acc[m][n] = __builtin_amdgcn_mfma_f32_16x16x32_bf16(wf[m], xf[n], acc[m][n], 0, 0, 0);
    __builtin_amdgcn_s_setprio(0);
    #pragma unroll
    for (int m = 0; m < 4; ++m) wf[m] = *(const bf16x8*)(Ws + woff[4 + m]);
    __builtin_amdgcn_s_setprio(1);
    #pragma unroll
    for (int m = 0; m < 4; ++m)
      #pragma unroll
      for (int n = 0; n < 4; ++n)
        acc[4 + m][n] = __builtin_amdgcn_mfma_f32_16x16x32_bf16(wf[m], xf[n], acc[4 + m][n], 0, 0, 0);
    __builtin_amdgcn_s_setprio(0);
    if (kt <= 13) { VMW(6); } else if (kt == 14) { VMW(0); }
    LGKM0();
    __builtin_amdgcn_s_barrier();
  }

  // ---- epilogue: 2 phases of 128 tokens (64 KB restage each) ----
  const bool doElu = (fb < 4);
  const int b = (int)(tok0 >> 12);
  const int nn0 = (int)(tok0 & 4095);
  #pragma unroll
  for (int p = 0; p < 2; ++p) {
    if (p) __syncthreads();  // phase-0 reads done before phase-1 writes
    if ((wc >> 1) == p) {    // waves owning tokens [p*128, p*128+128)
      #pragma unroll
      for (int m = 0; m < 8; ++m) {
        const int feat = wr * 128 + m * 16 + lkb * 4;
        const int ub = feat >> 3, bo = (feat & 7) * 2;
        #pragma unroll
        for (int n = 0; n < 4; ++n) {
          const int trow = (wc & 1) * 64 + n * 16 + lrow;  // local token row 0..127
          bf16x4 o;
          #pragma unroll
          for (int j = 0; j < 4; ++j) {
            float v = acc[m][n][j];
            if (doElu) v = v > 0.f ? v + 1.f : __expf(v);
            o[j] = (bf16_t)v;
          }
          const int s = (trow ^ (trow >> 3)) & 7;
          *(bf16x4*)(smem + trow * 512 + ((ub ^ s) << 4) + bo) = o;
        }
      }
    }
    __syncthreads();
    if (fb < 2) {
      // q: rows = tokens, coalesced bf16x8
      #pragma unroll
      for (int i = 0; i < 8; ++i) {
        const int flat = i * 512 + t;
        const int trow = flat >> 5, u = flat & 31;
        const int s = (trow ^ (trow >> 3)) & 7;
        bf16x8 vv = *(const bf16x8*)(smem + trow * 512 + ((u ^ s) << 4));
        *(bf16x8*)&q_phi[(tok0 + p * 128 + trow) * 512 + f0 + u * 8] = vv;
      }
    } else {
      // k/v: transposed out, 8 scalar LDS reads -> bf16x8 store
      bf16_t* base = (fb < 4) ? (kT + ((size_t)(b * 512 + (fb - 2) * 256)) * 4096)
                              : (vT + ((size_t)(b * 512 + (fb - 4) * 256)) * 4096);
      #pragma unroll
      for (int i = 0; i < 8; ++i) {
        const int flat = i * 512 + t;
        const int fl = flat >> 4, tg = flat & 15;
        const int ub = fl >> 3, bo = (fl & 7) * 2;
        bf16x8 vv;
        #pragma unroll
        for (int j = 0; j < 8; ++j) {
          const int tok = tg * 8 + j;
          const int s = (tok ^ (tok >> 3)) & 7;
          vv[j] = *(const bf16_t*)(smem + tok * 512 + ((ub ^ s) << 4) + bo);
        }
        *(bf16x8*)(base + (size_t)fl * 4096 + nn0 + p * 128 + tg * 8) = vv;
      }
    }
  }
}

// ---------------- kv[f][d] = sum_n kT[f][n]*vT[d][n]; ksum[f] = sum_n kT[f][n] ----
__global__ __launch_bounds__(256) void kv_mfma(const bf16_t* __restrict__ kT,
                                               const bf16_t* __restrict__ vT,
                                               float* __restrict__ kv,
                                               float* __restrict__ ksum) {
  const int bh = blockIdx.x;
  const int nbase = blockIdx.y * 512;
  __shared__ alignas(16) char smem[32768];  // 2 bufs x (K 8K + V 8K)
  const int t = threadIdx.x, w = t >> 6, l = t & 63;
  const int wr = w >> 1, wc = w & 1;
  const int lrow = l & 15, lkb = l >> 4;
  const int st_r = l >> 3;
  const int st_c = ((l & 7) ^ st_r) * 8;
  const bf16_t* Kp = kT + (size_t)bh * 64 * 4096;
  const bf16_t* Vp = vT + (size_t)bh * 64 * 4096;

  f32x4 acc[2][2];
  #pragma unroll
  for (int m = 0; m < 2; ++m)
    #pragma unroll
    for (int n = 0; n < 2; ++n) acc[m][n] = f32x4{0.f, 0.f, 0.f, 0.f};
  float ksf[2] = {0.f, 0.f};

  #pragma unroll
  for (int c = 0; c < 2; ++c) {
    const int q8 = w * 2 + c;
    gload16(Kp + (size_t)(q8 * 8 + st_r) * 4096 + nbase + st_c, smem + q8 * 1024);
    gload16(Vp + (size_t)(q8 * 8 + st_r) * 4096 + nbase + st_c, smem + 8192 + q8 * 1024);
  }
  __syncthreads();

  int cur = 0;
  for (int st = 0; st < 8; ++st) {
    if (st < 7) {
      char* nb = smem + (cur ^ 1) * 16384;
      const int nb2 = nbase + (st + 1) * 64;
      #pragma unroll
      for (int c = 0; c < 2; ++c) {
        const int q8 = w * 2 + c;
        gload16(Kp + (size_t)(q8 * 8 + st_r) * 4096 + nb2 + st_c, nb + q8 * 1024);
        gload16(Vp + (size_t)(q8 * 8 + st_r) * 4096 + nb2 + st_c, nb + 8192 + q8 * 1024);
      }
    }
    const char* KsB = smem + cur * 16384;
    const char* VsB = KsB + 8192;
    bf16x8 af[2][2], bf[2][2];
    #pragma unroll
    for (int m = 0; m < 2; ++m) {
      const int r = wr * 32 + m * 16 + lrow;
      #pragma unroll
      for (int kk = 0; kk < 2; ++kk) {
        const int kb = lkb + kk * 4;
        af[m][kk] = *(const bf16x8*)(KsB + r * 128 + (((kb ^ (r & 7)) & 7) << 4));
      }
    }
    #pragma unroll
    for (int n = 0; n < 2; ++n) {
      const int r = wc * 32 + n * 16 + lrow;
      #pragma unroll
      for (int kk = 0; kk < 2; ++kk) {
        const int kb = lkb + kk * 4;
        bf[n][kk] = *(const bf16x8*)(VsB + r * 128 + (((kb ^ (r & 7)) & 7) << 4));
      }
    }
    #pragma unroll
    for (int m = 0; m < 2; ++m)
      #pragma unroll
      for (int n = 0; n < 2; ++n) {
        acc[m][n] = __builtin_amdgcn_mfma_f32_16x16x32_bf16(af[m][0], bf[n][0], acc[m][n], 0, 0, 0);
        acc[m][n] = __builtin_amdgcn_mfma_f32_16x16x32_bf16(af[m][1], bf[n][1], acc[m][n], 0, 0, 0);
      }
    if (wc == 0) {
      #pragma unroll
      for (int m = 0; m < 2; ++m)
        #pragma unroll
        for (int kk = 0; kk < 2; ++kk)
          #pragma unroll
          for (int j = 0; j < 8; ++j) ksf[m] += (float)af[m][kk][j];
    }
    __syncthreads();
    cur ^= 1;
  }

  float* kvp = kv + (size_t)bh * 4096;
  #pragma unroll
  for (int m = 0; m < 2; ++m)
    #pragma unroll
    for (int n = 0; n < 2; ++n)
      #pragma unroll
      for (int j = 0; j < 4; ++j)
        atomicAdd(&kvp[(wr * 32 + m * 16 + lkb * 4 + j) * 64 + wc * 32 + n * 16 + lrow],
                  acc[m][n][j]);
  if (wc == 0) {
    #pragma unroll
    for (int m = 0; m < 2; ++m) {
      float s = ksf[m];
      s += __shfl_xor(s, 16);
      s += __shfl_xor(s, 32);
      if (l < 16) atomicAdd(&ksum[(size_t)bh * 64 + wr * 32 + m * 16 + l], s);
    }
  }
}

// ---------------- W2T[b][j][h*64+f] = sum_d kv[b,h,f,d] * w_proj[h*64+d][j] ----------------
__global__ __launch_bounds__(256) void w2_kernel(const float* __restrict__ kv,
                                                 const float* __restrict__ w_proj,
                                                 bf16_t* __restrict__ W2T) {
  const int bh = blockIdx.x, b = bh >> 3, h = bh & 7;
  const int j0 = blockIdx.y * 64;
  const int t = threadIdx.x;
  __shared__ float kvs[64][64];
  __shared__ float wps[64][64];
  const float* kvp = kv + (size_t)bh * 4096;
  #pragma unroll
  for (int i = 0; i < 16; ++i) ((float*)kvs)[t + 256 * i] = kvp[t + 256 * i];
  {
    const int d = t >> 2, c16 = (t & 3) * 16;
    const float* src = w_proj + (size_t)(h * 64 + d) * 512 + j0 + c16;
    #pragma unroll
    for (int j = 0; j < 16; ++j) wps[d][c16 + j] = src[j];
  }
  __syncthreads();
  const int fq = t >> 4, jq = t & 15;
  float acc[4][4] = {};
  for (int d = 0; d < 64; ++d) {
    float kf[4], wj[4];
    #pragma unroll
    for (int i = 0; i < 4; ++i) kf[i] = kvs[fq * 4 + i][d];
    #pragma unroll
    for (int i = 0; i < 4; ++i) wj[i] = wps[d][jq * 4 + i];
    #pragma unroll
    for (int i = 0; i < 4; ++i)
      #pragma unroll
      for (int j = 0; j < 4; ++j) acc[i][j] += kf[i] * wj[j];
  }
  #pragma unroll
  for (int j = 0; j < 4; ++j)
    #pragma unroll
    for (int i = 0; i < 4; ++i)
      W2T[((size_t)b * 512 + j0 + jq * 4 + j) * 512 + h * 64 + fq * 4 + i] = (bf16_t)acc[i][j];
}

// ==================== output GEMM v2: fused z-scale (zq) in B-staging ====================
__global__ __launch_bounds__(256) void gemm_out(const bf16_t* __restrict__ W2T,
                                                const bf16_t* __restrict__ q_phi,
                                                const float* __restrict__ ksum,
                                                float* __restrict__ Cout,
                                                const float* __restrict__ bias) {
  __shared__ alignas(16) char smem[67584];  // A [0,32K) x2; B [32K,64K) x2; ksum [64K,66K)
  const int t = threadIdx.x, w = t >> 6, l = t & 63;
  const int hw = blockIdx.x;
  const int bid = (hw & 7) * 128 + (hw >> 3);   // 1024/8=128
  const int z = bid >> 7;
  const int rem = bid & 127;
  const int qblk = rem >> 2, pblk = rem & 3;
  const size_t tok0 = (size_t)qblk * 128;
  const int pj0 = pblk * 128;
  const bf16_t* Pp = W2T + ((size_t)z * 512 + pj0) * 512;

  const int wr = w >> 1, wc = w & 1;
  const int lrow = l & 15, lkb = l >> 4;
  const int st_r = l >> 3;
  const int st_c = ((l & 7) ^ st_r) * 8;
  const int token = t >> 1, half = t & 1;
  float* ks_lds = (float*)(smem + 65536);

  bf16x8 breg[4];
  auto loadB = [&](int c) {
    const bf16_t* p = q_phi + ((size_t)z * 4096 + tok0 + token) * 512 + c * 64 + half * 32;
    breg[0] = *(const bf16x8*)p;
    breg[1] = *(const bf16x8*)(p + 8);
    breg[2] = *(const bf16x8*)(p + 16);
    breg[3] = *(const bf16x8*)(p + 24);
  };
  auto stageA = [&](int s) {
    #pragma unroll
    for (int c = 0; c < 4; ++c) {
      const int q8 = c * 4 + w;
      gload16(Pp + (size_t)(q8 * 8 + st_r) * 512 + s * 64 + st_c,
              smem + (s & 1) * 16384 + q8 * 1024);
    }
  };
  auto procB = [&](int c) {
    const f32x4* ksv = (const f32x4*)(ks_lds + c * 64 + half * 32);
    float vals[32];
    float dot = 0.f;
    #pragma unroll
    for (int g = 0; g < 8; ++g) {
      const f32x4 kk = ksv[g];
      #pragma unroll
      for (int j = 0; j < 4; ++j) {
        const float v = (float)breg[g >> 1][(g & 1) * 4 + j];
        vals[g * 4 + j] = v;
        dot += v * kk[j];
      }
    }
    dot += __shfl_xor(dot, 1);  // lanes 2i,2i+1 share a token
    const float zz = 1.f / dot;
    char* dst = smem + 32768 + (c & 1) * 16384;
    #pragma unroll
    for (int g = 0; g < 4; ++g) {
      bf16x8 o;
      #pragma unroll
      for (int j = 0; j < 8; ++j) o[j] = (bf16_t)(vals[g * 8 + j] * zz);
      const int uk = half * 4 + g;
      *(bf16x8*)(dst + token * 128 + ((uk ^ (token & 7)) << 4)) = o;
    }
  };

  // prologue: ksum -> LDS; then chunk 0 staged
  {
    const f32x2 kk = *(const f32x2*)&ksum[(size_t)z * 512 + t * 2];
    *(f32x2*)&ks_lds[t * 2] = kk;
  }
  __syncthreads();
  loadB(0);
  stageA(0);
  procB(0);
  VMW(0);
  __syncthreads();

  f32x4 acc[4][4];
  #pragma unroll
  for (int m = 0; m < 4; ++m)
    #pragma unroll
    for (int n = 0; n < 4; ++n) acc[m][n] = f32x4{0.f, 0.f, 0.f, 0.f};

  for (int kt = 0; kt < 8; ++kt) {
    const char* PsB = smem + (kt & 1) * 16384;
    const char* QsB = smem + 32768 + (kt & 1) * 16384;
    bf16x8 pf[4][2], qf[4][2];
    #pragma unroll
    for (int m = 0; m < 4; ++m) {
      const int r = wr * 64 + m * 16 + lrow;
      #pragma unroll
      for (int kk = 0; kk < 2; ++kk) {
        const int kb = lkb + kk * 4;
        pf[m][kk] = *(const bf16x8*)(PsB + r * 128 + (((kb ^ (r & 7)) & 7) << 4));
      }
    }
    #pragma unroll
    for (int n = 0; n < 4; ++n) {
      const int r = wc * 64 + n * 16 + lrow;
      #pragma unroll
      for (int kk = 0; kk < 2; ++kk) {
        const int kb = lkb + kk * 4;
        qf[n][kk] = *(const bf16x8*)(QsB + r * 128 + (((kb ^ (r & 7)) & 7) << 4));
      }
    }
    if (kt + 1 < 8) { loadB(kt + 1); stageA(kt + 1); }
    #pragma unroll
    for (int m = 0; m < 4; ++m)
      #pragma unroll
      for (int n = 0; n < 4; ++n) {
        acc[m][n] = __builtin_amdgcn_mfma_f32_16x16x32_bf16(pf[m][0], qf[n][0], acc[m][n], 0, 0, 0);
        acc[m][n] = __builtin_amdgcn_mfma_f32_16x16x32_bf16(pf[m][1], qf[n][1], acc[m][n], 0, 0, 0);
      }
    if (kt + 1 < 8) { procB(kt + 1); VMW(0); }
    __syncthreads();
  }

  // epilogue: two phases of [64 token-rows][128 j] f32 (32 KB each) in smem[0,32K)
  float* ep = (float*)smem;
  #pragma unroll
  for (int p = 0; p < 2; ++p) {
    if (p) __syncthreads();
    #pragma unroll
    for (int nn2 = 0; nn2 < 2; ++nn2) {
      const int n = p * 2 + nn2;
      const int r6 = wc * 32 + (n & 1) * 16 + lrow;
      #pragma unroll
      for (int m = 0; m < 4; ++m) {
        const int pr0 = wr * 64 + m * 16 + lkb * 4;
        f32x4 v = acc[m][n];
        const f32x4 bv = *(const f32x4*)&bias[pj0 + pr0];
        #pragma unroll
        for (int j = 0; j < 4; ++j) v[j] += bv[j];
        const int u = pr0 >> 2;
        *(f32x4*)((char*)ep + r6 * 512 + ((u ^ (r6 & 31)) << 4)) = v;
      }
    }
    __syncthreads();
    #pragma unroll
    for (int i = 0; i < 8; ++i) {
      const int flat = i * 256 + t;
      const int r6 = flat >> 5, u2 = flat & 31;
      f32x4 v = *(const f32x4*)((char*)ep + r6 * 512 + ((u2 ^ (r6 & 31)) << 4));
      const int qc = (r6 >> 5) * 64 + p * 32 + (r6 & 31);
      *(f32x4*)&Cout[((size_t)z * 4096 + tok0 + qc) * 512 + pj0 + u2 * 4] = v;
    }
  }
}

extern "C" void kernel_launch(void* const* d_in, const int* in_sizes, int n_in,
                              void* d_out, int out_size, void* d_ws, size_t ws_size,
                              hipStream_t stream) {
  const float* x      = (const float*)d_in[0];
  const float* w_qkv  = (const float*)d_in[1];
  const float* proj   = (const float*)d_in[2];
  const float* w_proj = (const float*)d_in[3];
  const float* b_proj = (const float*)d_in[4];
  float* out = (float*)d_out;
  char* ws = (char*)d_ws;

  // workspace layout (bytes)
  bf16_t* WeffT = (bf16_t*)(ws + 0);           // 1536*512*2   =  1,572,864
  bf16_t* q_phi = (bf16_t*)(ws + 1572864);     // 32768*512*2  = 33,554,432
  bf16_t* kT    = (bf16_t*)(ws + 35127296);    // 64*64*4096*2 = 33,554,432
  bf16_t* vT    = (bf16_t*)(ws + 68681728);    // 64*64*4096*2 = 33,554,432
  float*  kv    = (float*)(ws + 102236160);    // 64*64*64*4   =  1,048,576
  float*  ksum  = (float*)(ws + 103284736);    // 64*64*4      =     16,384
  bf16_t* W2T   = (bf16_t*)(ws + 103301120);   // 8*512*512*2  =  4,194,304
                                               // total 107,495,424

  prep_qk<<<dim3(16, 8), 256, 0, stream>>>(w_qkv, proj, WeffT);
  prep_v<<<dim3(16, 16), 256, 0, stream>>>(w_qkv, WeffT);
  gemm_qkv8<<<768, 512, 0, stream>>>(x, WeffT, q_phi, kT, vT);
  hipMemsetAsync(kv, 0, 1048576 + 16384, stream);
  kv_mfma<<<dim3(64, 8), 256, 0, stream>>>(kT, vT, kv, ksum);
  w2_kernel<<<dim3(64, 8), 256, 0, stream>>>(kv, w_proj, W2T);
  gemm_out<<<1024, 256, 0, stream>>>(W2T, q_phi, ksum, out, b_proj);
}